// Round 2
// baseline (240.593 us; speedup 1.0000x reference)
//
#include <hip/hip_runtime.h>
#include <math.h>

#define DD 8
#define ZD 16
#define HID 200
#define EPSL 0.1f
#define BS 8           // samples per block (halved: 2 blocks/CU)
#define NTHREADS 1024  // 16 waves
#define NKC 7          // K chunks of 32 (200 -> 224)
#define NMT 13         // unit tiles of 16 (200 -> 208)
#define XSTR 216       // halfs per X row (432B: 16B-aligned, 2-way-free)
#define CSTR 208       // halfs per coeff row (416B: 16B-aligned)
#define BSTR 200       // halfs per bsh row
#define W0STR 200      // halfs per w0t row
#define HSTR 16        // floats per Hr row
#define NT4 2          // n-tiles per wave in T phase (64 rows total)

#define KSC 1024.0f
#define SSC 64.0f
#define INV_K (1.0f/1024.0f)
#define INV_KS (1.0f/65536.0f)

typedef _Float16 half8 __attribute__((ext_vector_type(8)));
typedef _Float16 half4v __attribute__((ext_vector_type(4)));
typedef _Float16 half2v __attribute__((ext_vector_type(2)));
typedef float float4v __attribute__((ext_vector_type(4)));

#define S4 (NKC*NMT*64*8)
#define OFF_W1T 0
#define OFF_W2T (S4)
#define OFF_W1  (2*S4)
#define OFF_W2  (3*S4)
#define OFF_W0T (4*S4)
#define OFF_W0  (4*S4 + NMT*64*8)
#define WS_HALFS (4*S4 + NMT*64*8 + NKC*64*8)

// ---- LDS layout (units: _Float16). Total 40896 halfs = 81792 B -> 2 blocks/CU.
#define CFSZ  (8*CSTR)                    // 1664
#define O_XT  0                           // 64 rows + 8-half zero guard
#define O_XB  (O_XT + 64*XSTR + 8)        // 64 rows (row63 k-tail -> Cf0 row0, finite)
#define O_CF  (O_XB + 64*XSTR)            // Cf[5] 8 rows each
#define O_U   (O_CF + 5*CFSZ)             // union{ FB 8 rows+guard (1736) ; Hr 64x16 f32 (2048) }
#define O_XZ  (O_U + 2048)                // z staging 8x40 (F0 rows 8-15 read beyond: garbage OK)
#define O_GSH (O_XZ + 320)                // 8x8 f32
#define O_BSH (O_GSH + 128)               // b0,b1,b2,KSC*W3 @200
#define O_W0T (O_BSH + 4*BSTR)            // SSC*W0[8+t][u] @200 + 24 zero tail
#define SMEM_HALFS (O_W0T + 8*W0STR + 24) // 40896

// ---------------------------------------------------------------------------
__global__ void prep(const float* __restrict__ W0, const float* __restrict__ W1,
                     const float* __restrict__ W2, _Float16* __restrict__ ws)
{
    int idx = blockIdx.x * 256 + threadIdx.x;
    if (idx >= WS_HALFS) return;
    float v = 0.f;
    if (idx < 4*S4) {
        int arr = idx / S4, e = idx % S4;
        int kc = e / (NMT*64*8); int r = e % (NMT*64*8);
        int mt = r / (64*8); r %= 64*8;
        int lane = r / 8, j = r % 8;
        int m = mt*16 + (lane & 15);
        int k = kc*32 + (lane >> 4)*8 + j;
        if (m < HID && k < HID) {
            if      (arr == 0) v = W1[k*HID + m];
            else if (arr == 1) v = W2[k*HID + m];
            else if (arr == 2) v = W1[m*HID + k];
            else               v = W2[m*HID + k];
        }
    } else if (idx < OFF_W0) {
        int e = idx - OFF_W0T;
        int mt = e / (64*8); int r = e % (64*8);
        int lane = r / 8, j = r % 8;
        int m = mt*16 + (lane & 15);
        int k = (lane >> 4)*8 + j;
        if (m < HID && k < ZD) v = W0[k*HID + m];
    } else {
        int e = idx - OFF_W0;
        int kc = e / (64*8); int r = e % (64*8);
        int lane = r / 8, j = r % 8;
        int m = (lane & 15);
        int k = kc*32 + (lane >> 4)*8 + j;
        if (k < HID) v = W0[m*HID + k];
    }
    ws[idx] = (_Float16)v;
}

// ---------------------------------------------------------------------------
__device__ __forceinline__ half4v pk4(float4v a) {
    half2v lo = __builtin_bit_cast(half2v, __builtin_amdgcn_cvt_pkrtz(a.x, a.y));
    half2v hi = __builtin_bit_cast(half2v, __builtin_amdgcn_cvt_pkrtz(a.z, a.w));
    return __builtin_shufflevector(lo, hi, 0, 1, 2, 3);
}
__device__ __forceinline__ void sig_sp(float x, float& sp, float& sg) {
    float e = __expf(-fabsf(x));
    float r = 1.0f / (1.0f + e);
    sg = (x >= 0.f) ? r : (1.0f - r);
    sp = fmaxf(x, 0.f) + __logf(1.f + e);
}

template<int NTILES>
__device__ __forceinline__ void run_mv(const half8* __restrict__ Asw,
                                       const _Float16* __restrict__ Xsrc,
                                       int mt0, int mtc, int lane,
                                       float4v acc[2][NTILES])
{
    const int lm = lane & 15, q = lane >> 4;
#pragma unroll
    for (int m = 0; m < 2; ++m)
#pragma unroll
        for (int n = 0; n < NTILES; ++n)
            acc[m][n] = (float4v){0.f, 0.f, 0.f, 0.f};
    for (int kc = 0; kc < NKC; ++kc) {
        half8 a[2];
#pragma unroll
        for (int m = 0; m < 2; ++m)
            if (m < mtc) a[m] = Asw[(kc*NMT + mt0 + m)*64 + lane];
        half8 x[NTILES];
#pragma unroll
        for (int n = 0; n < NTILES; ++n)
            x[n] = *(const half8*)(Xsrc + (n*16 + lm)*XSTR + kc*32 + q*8);
#pragma unroll
        for (int m = 0; m < 2; ++m)
            if (m < mtc)
#pragma unroll
                for (int n = 0; n < NTILES; ++n)
                    acc[m][n] = __builtin_amdgcn_mfma_f32_16x16x32_f16(a[m], x[n], acc[m][n], 0, 0, 0);
    }
}

// ---------------------------------------------------------------------------
__global__ void __launch_bounds__(NTHREADS, 8)   // 8 waves/EU -> VGPR<=64 -> 2 blocks/CU
lnn_main(const float* __restrict__ z,
         const float* __restrict__ W0, const float* __restrict__ b0,
         const float* __restrict__ b1, const float* __restrict__ b2,
         const float* __restrict__ W3,
         const _Float16* __restrict__ ws,
         float* __restrict__ out)
{
    __shared__ alignas(16) _Float16 smem[SMEM_HALFS];
    _Float16* const Xt  = smem + O_XT;
    _Float16* const Xb  = smem + O_XB;
    _Float16* const Cf  = smem + O_CF;
    _Float16* const bsh = smem + O_BSH;
    _Float16* const w0t = smem + O_W0T;
    _Float16* const Xz  = smem + O_XZ;
    float*    const gsh = (float*)(smem + O_GSH);
    float*    const Hr  = (float*)(smem + O_U);
    _Float16* const FB  = smem + O_U;    // F/B 8-row chain; rows 8-15 read beyond (garbage, contained)

    const int tid  = threadIdx.x;
    const int wave = tid >> 6;
    const int lane = tid & 63;
    const int lm   = lane & 15;
    const int q    = lane >> 4;
    const int sq   = lane & 7;   // sample index within interleaved rows
    const int tq   = (lane >> 3) & 1; // tangent sub-row
    const int s0   = blockIdx.x * BS;

    // T-phase wave grid: 8 m-groups x 2 n-groups (4 n-tiles of 16 rows total)
    const int twm  = wave >> 1;
    const int twn  = wave & 1;
    const int mt0t = (twm < 5) ? twm*2 : (twm + 5);
    const int mtct = (twm < 5) ? 2 : 1;

    const half8* W1Tsw = (const half8*)(ws + OFF_W1T);
    const half8* W2Tsw = (const half8*)(ws + OFF_W2T);
    const half8* W1sw  = (const half8*)(ws + OFF_W1);
    const half8* W2sw  = (const half8*)(ws + OFF_W2);
    const half8* W0Tsw = (const half8*)(ws + OFF_W0T);
    const half8* W0sw  = (const half8*)(ws + OFF_W0);

    // ---- init/staging ----
    if (tid < 128) {
        int s = tid >> 4, k = tid & 15;
        Xz[s*40 + k]      = (_Float16)z[(s0 + s)*ZD + k];
        Xz[s*40 + 16 + k] = (_Float16)0.f;
    }
    for (int idx = tid; idx < 64*16; idx += NTHREADS) {
        int r = idx >> 4, c = 200 + (idx & 15);
        Xt[r*XSTR + c] = (_Float16)0.f;
        Xb[r*XSTR + c] = (_Float16)0.f;
    }
    for (int idx = tid; idx < 8*16; idx += NTHREADS) {   // FB k-tail cols, rows 0-7
        int r = idx >> 4, c = 200 + (idx & 15);
        FB[r*XSTR + c] = (_Float16)0.f;
    }
    if (tid < 8) {
        Xt[64*XSTR + tid] = (_Float16)0.f;   // Xt row-63 kc6/q3 overflow guard
        FB[8*XSTR + tid]  = (_Float16)0.f;   // FB row-7 overflow guard
    }
    for (int idx = tid; idx < 4*BSTR; idx += NTHREADS) {
        int l = idx / BSTR, u = idx % BSTR;
        float v;
        if      (l == 0) v = b0[u];
        else if (l == 1) v = b1[u];
        else if (l == 2) v = b2[u];
        else             v = KSC * W3[u];
        bsh[idx] = (_Float16)v;
    }
    for (int idx = tid; idx < 8*W0STR + 24; idx += NTHREADS) {
        int t = idx / W0STR, u = idx % W0STR;
        w0t[idx] = (_Float16)((t < 8) ? SSC * W0[(DD + t)*HID + u] : 0.f);
    }
    __syncthreads();

    float4v acc1[2][1];
    float4v acc4[2][NT4];
    const int ubf = wave*16 + q*4;   // F-duty unit base (wave<13)

    // ================= F0: a0 = z@W0+b0 -> FB, Cf0 (rows lm<8 only) =================
    if (wave < NMT) {
        acc1[0][0] = (float4v){0.f,0.f,0.f,0.f};
        half8 xz = *(const half8*)(Xz + lm*40 + q*8);
        half8 aw = W0Tsw[wave*64 + lane];
        acc1[0][0] = __builtin_amdgcn_mfma_f32_16x16x32_f16(aw, xz, acc1[0][0], 0, 0, 0);
        if (lm < 8) {
            half4v bb = *(const half4v*)(&bsh[0*BSTR + ubf]);
            float h[4], p[4];
#pragma unroll
            for (int r = 0; r < 4; ++r) {
                float av = acc1[0][0][r] + (float)bb[r];
                sig_sp(av, h[r], p[r]);
            }
            *(half4v*)(&FB[lm*XSTR + ubf])        = pk4((float4v){h[0],h[1],h[2],h[3]});
            *(half4v*)(&Cf[0*CFSZ + lm*CSTR + ubf]) = pk4((float4v){p[0],p[1],p[2],p[3]});
        }
    }
    __syncthreads();

    // ================= F1 =================
    if (wave < NMT) run_mv<1>(W1Tsw, FB, wave, 1, lane, acc1);
    __syncthreads();
    if (wave < NMT && lm < 8) {
        half4v bb = *(const half4v*)(&bsh[1*BSTR + ubf]);
        float h[4], p[4];
#pragma unroll
        for (int r = 0; r < 4; ++r) {
            float av = acc1[0][0][r] + (float)bb[r];
            sig_sp(av, h[r], p[r]);
        }
        *(half4v*)(&FB[lm*XSTR + ubf])          = pk4((float4v){h[0],h[1],h[2],h[3]});
        *(half4v*)(&Cf[1*CFSZ + lm*CSTR + ubf]) = pk4((float4v){p[0],p[1],p[2],p[3]});
    }
    __syncthreads();

    // ========= P2: T2 (th0 on-the-fly) || F2 =========
    {
#pragma unroll
        for (int m = 0; m < 2; ++m)
#pragma unroll
            for (int n = 0; n < NT4; ++n)
                acc4[m][n] = (float4v){0.f, 0.f, 0.f, 0.f};
        for (int kc = 0; kc < NKC; ++kc) {
            half8 a[2];
#pragma unroll
            for (int m = 0; m < 2; ++m)
                if (m < mtct) a[m] = W1Tsw[(kc*NMT + mt0t + m)*64 + lane];
            half8 p0 = *(const half8*)(Cf + 0*CFSZ + sq*CSTR + kc*32 + q*8);
            half8 x[NT4];
#pragma unroll
            for (int n = 0; n < NT4; ++n) {
                int t = 2*(twn*NT4 + n) + tq;
                half8 w0 = *(const half8*)(w0t + t*W0STR + kc*32 + q*8);
                x[n] = p0 * w0;   // th0 = p0 .* (S*W0row), in-register
            }
#pragma unroll
            for (int m = 0; m < 2; ++m)
                if (m < mtct)
#pragma unroll
                    for (int n = 0; n < NT4; ++n)
                        acc4[m][n] = __builtin_amdgcn_mfma_f32_16x16x32_f16(a[m], x[n], acc4[m][n], 0, 0, 0);
        }
        if (wave < NMT) run_mv<1>(W2Tsw, FB, wave, 1, lane, acc1);
    }
    __syncthreads();
#pragma unroll
    for (int m = 0; m < 2; ++m)
        if (m < mtct) {
            const int ub = (mt0t + m)*16 + q*4;
            half4v p1 = *(const half4v*)(&Cf[1*CFSZ + sq*CSTR + ub]);
#pragma unroll
            for (int n = 0; n < NT4; ++n) {
                int row = (twn*NT4 + n)*16 + lm;
                *(half4v*)(&Xt[row*XSTR + ub]) = pk4(acc4[m][n]) * p1;
            }
        }
    if (wave < NMT && lm < 8) {  // F2 epi: d2' -> FB, c2' -> Cf2
        half4v bb = *(const half4v*)(&bsh[2*BSTR + ubf]);
        half4v w3 = *(const half4v*)(&bsh[3*BSTR + ubf]);
        float d2[4], c2[4];
#pragma unroll
        for (int r = 0; r < 4; ++r) {
            float av = acc1[0][0][r] + (float)bb[r];
            float e = __expf(-fabsf(av));
            float rr = 1.f / (1.f + e);
            float sg = (av >= 0.f) ? rr : (1.f - rr);
            float wk = (float)w3[r];
            d2[r] = wk * sg;
            c2[r] = wk * sg * (1.f - sg);
        }
        *(half4v*)(&FB[lm*XSTR + ubf])          = pk4((float4v){d2[0],d2[1],d2[2],d2[3]});
        *(half4v*)(&Cf[2*CFSZ + lm*CSTR + ubf]) = pk4((float4v){c2[0],c2[1],c2[2],c2[3]});
    }
    __syncthreads();

    // ========= P3: T3 || B1 =========
    run_mv<NT4>(W2Tsw, Xt + twn*32*XSTR, mt0t, mtct, lane, acc4);
    if (wave < NMT) run_mv<1>(W2sw, FB, wave, 1, lane, acc1);
    __syncthreads();
#pragma unroll
    for (int m = 0; m < 2; ++m)
        if (m < mtct) {
            const int ub = (mt0t + m)*16 + q*4;
            half4v c2 = *(const half4v*)(&Cf[2*CFSZ + sq*CSTR + ub]);
#pragma unroll
            for (int n = 0; n < NT4; ++n) {
                int row = (twn*NT4 + n)*16 + lm;
                *(half4v*)(&Xb[row*XSTR + ub]) = pk4(acc4[m][n]) * c2;
            }
        }
    if (wave < NMT && lm < 8) {  // B1 epi
        half4v p1 = *(const half4v*)(&Cf[1*CFSZ + lm*CSTR + ubf]);
        half4v u1 = pk4(acc1[0][0]);
        half4v one = {(_Float16)1.f,(_Float16)1.f,(_Float16)1.f,(_Float16)1.f};
        *(half4v*)(&FB[lm*XSTR + ubf])          = u1 * p1;
        *(half4v*)(&Cf[3*CFSZ + lm*CSTR + ubf]) = u1 * (one - p1);
    }
    __syncthreads();

    // ========= P4: T4 || B0 =========
    run_mv<NT4>(W2sw, Xb + twn*32*XSTR, mt0t, mtct, lane, acc4);
    if (wave < NMT) run_mv<1>(W1sw, FB, wave, 1, lane, acc1);
    __syncthreads();
#pragma unroll
    for (int m = 0; m < 2; ++m)
        if (m < mtct) {
            const int ub = (mt0t + m)*16 + q*4;
            half4v p1 = *(const half4v*)(&Cf[1*CFSZ + sq*CSTR + ub]);
            half4v c3 = *(const half4v*)(&Cf[3*CFSZ + sq*CSTR + ub]);
#pragma unroll
            for (int n = 0; n < NT4; ++n) {
                int row = (twn*NT4 + n)*16 + lm;
                half4v th1 = *(const half4v*)(&Xt[row*XSTR + ub]);
                *(half4v*)(&Xb[row*XSTR + ub]) = pk4(acc4[m][n]) * p1 + c3 * th1;
            }
        }
    if (wave < NMT && lm < 8) {  // B0 epi
        half4v p0 = *(const half4v*)(&Cf[0*CFSZ + lm*CSTR + ubf]);
        half4v u0 = pk4(acc1[0][0]);
        half4v one = {(_Float16)1.f,(_Float16)1.f,(_Float16)1.f,(_Float16)1.f};
        half4v d0 = u0 * p0;
        *(half4v*)(&FB[lm*XSTR + ubf])          = d0;
        *(half4v*)(&Cf[4*CFSZ + lm*CSTR + ubf]) = d0 * (one - p0);
    }
    __syncthreads();

    // ========= P5: T5 || g-projection; no mid-barrier needed =========
    run_mv<NT4>(W1sw, Xb + twn*32*XSTR, mt0t, mtct, lane, acc4);
    if (wave == 13) {   // g = W0 d0'
        float4v g = (float4v){0.f,0.f,0.f,0.f};
        for (int kc = 0; kc < NKC; ++kc) {
            half8 a = W0sw[kc*64 + lane];
            half8 x = *(const half8*)(FB + lm*XSTR + kc*32 + q*8);
            g = __builtin_amdgcn_mfma_f32_16x16x32_f16(a, x, g, 0, 0, 0);
        }
        if (q < 2 && lm < 8) {
            float4v gv;
            gv.x = g.x*INV_K; gv.y = g.y*INV_K; gv.z = g.z*INV_K; gv.w = g.w*INV_K;
            *(float4v*)(&gsh[lm*8 + q*4]) = gv;
        }
    }
#pragma unroll
    for (int m = 0; m < 2; ++m)
        if (m < mtct) {
            const int ub = (mt0t + m)*16 + q*4;
            half4v p0 = *(const half4v*)(&Cf[0*CFSZ + sq*CSTR + ub]);
            half4v c4 = *(const half4v*)(&Cf[4*CFSZ + sq*CSTR + ub]);
#pragma unroll
            for (int n = 0; n < NT4; ++n) {
                int row = (twn*NT4 + n)*16 + lm;
                int t = 2*(twn*NT4 + n) + tq;
                half4v w0 = *(const half4v*)(&w0t[t*W0STR + ub]);
                *(half4v*)(&Xt[row*XSTR + ub]) = pk4(acc4[m][n]) * p0 + c4 * w0;
            }
        }
    __syncthreads();

    // ========= P6: Hr projection (waves 0-3; clobbers FB region -- FB dead) =========
    if (wave < 4) {
        float4v hacc = (float4v){0.f,0.f,0.f,0.f};
        for (int kc = 0; kc < NKC; ++kc) {
            half8 a = W0sw[kc*64 + lane];
            half8 x = *(const half8*)(Xt + (wave*16 + lm)*XSTR + kc*32 + q*8);
            hacc = __builtin_amdgcn_mfma_f32_16x16x32_f16(a, x, hacc, 0, 0, 0);
        }
        int row = wave*16 + lm;
        float4v hv;
        hv.x = hacc.x*INV_KS; hv.y = hacc.y*INV_KS;
        hv.z = hacc.z*INV_KS; hv.w = hacc.w*INV_KS;
        *(float4v*)(&Hr[row*HSTR + q*4]) = hv;
    }
    __syncthreads();

    // ========= per-sample 8x8 solve (8 threads) =========
    if (tid < BS) {
        const int s = tid;
        float M[DD][DD], F[DD], v[DD], a[DD];
#pragma unroll
        for (int c = 0; c < DD; ++c) v[c] = z[(s0 + s)*ZD + DD + c];
#pragma unroll
        for (int r = 0; r < DD; ++r) {
            float f = gsh[s*8 + r];
#pragma unroll
            for (int c = 0; c < DD; ++c) {
                M[r][c] = Hr[(r*8 + s)*HSTR + DD + c] + ((r == c) ? 2.f*EPSL : 0.f);
                f -= Hr[(r*8 + s)*HSTR + c] * v[c];
            }
            F[r] = f;
        }
#pragma unroll
        for (int col = 0; col < DD; ++col) {
            const float inv = 1.f / M[col][col];
#pragma unroll
            for (int r = col + 1; r < DD; ++r) {
                const float fac = M[r][col] * inv;
#pragma unroll
                for (int c = col + 1; c < DD; ++c) M[r][c] -= fac * M[col][c];
                F[r] -= fac * F[col];
            }
        }
#pragma unroll
        for (int r = DD - 1; r >= 0; --r) {
            float ssum = F[r];
#pragma unroll
            for (int c = r + 1; c < DD; ++c) ssum -= M[r][c] * a[c];
            a[r] = ssum / M[r][r];
        }
        float* op = out + (size_t)(s0 + s)*ZD;
#pragma unroll
        for (int c = 0; c < DD; ++c) { op[c] = v[c]; op[DD + c] = a[c]; }
    }
}

extern "C" void kernel_launch(void* const* d_in, const int* in_sizes, int n_in,
                              void* d_out, int out_size, void* d_ws, size_t ws_size,
                              hipStream_t stream)
{
    const float* z  = (const float*)d_in[1];
    const float* W0 = (const float*)d_in[2];
    const float* b0 = (const float*)d_in[3];
    const float* W1 = (const float*)d_in[4];
    const float* b1 = (const float*)d_in[5];
    const float* W2 = (const float*)d_in[6];
    const float* b2 = (const float*)d_in[7];
    const float* W3 = (const float*)d_in[8];
    float* out = (float*)d_out;
    _Float16* ws = (_Float16*)d_ws;

    const int n = in_sizes[1] / (2*DD);

    prep<<<dim3((WS_HALFS + 255)/256), dim3(256), 0, stream>>>(W0, W1, W2, ws);
    lnn_main<<<dim3(n / BS), dim3(NTHREADS), 0, stream>>>(
        z, W0, b0, b1, b2, W3, ws, out);
}

// Round 3
// 170.204 us; speedup vs baseline: 1.4136x; 1.4136x over previous
//
#include <hip/hip_runtime.h>
#include <math.h>

#define DD 8
#define ZD 16
#define HID 200
#define EPSL 0.1f
#define BS 8           // samples per block
#define NTHREADS 512   // 8 waves: 2 blocks/CU at 4 waves/EU, VGPR cap 128 (no spill)
#define NKC 7          // K chunks of 32 (200 -> 224)
#define NMT 13         // unit tiles of 16 (200 -> 208)
#define XSTR 216       // halfs per X row
#define CSTR 208       // halfs per coeff row
#define BSTR 200       // halfs per bsh row
#define W0STR 200      // halfs per w0t row
#define HSTR 16        // floats per Hr row
#define NT4 4          // n-tiles per wave in T phase (all 64 rows)

#define KSC 1024.0f
#define SSC 64.0f
#define INV_K (1.0f/1024.0f)
#define INV_KS (1.0f/65536.0f)

typedef _Float16 half8 __attribute__((ext_vector_type(8)));
typedef _Float16 half4v __attribute__((ext_vector_type(4)));
typedef _Float16 half2v __attribute__((ext_vector_type(2)));
typedef float float4v __attribute__((ext_vector_type(4)));

#define S4 (NKC*NMT*64*8)
#define OFF_W1T 0
#define OFF_W2T (S4)
#define OFF_W1  (2*S4)
#define OFF_W2  (3*S4)
#define OFF_W0T (4*S4)
#define OFF_W0  (4*S4 + NMT*64*8)
#define WS_HALFS (4*S4 + NMT*64*8 + NKC*64*8)

// ---- LDS layout (units: _Float16). Total 40896 halfs = 81792 B -> 2 blocks/CU.
#define CFSZ  (8*CSTR)
#define O_XT  0
#define O_XB  (O_XT + 64*XSTR + 8)
#define O_CF  (O_XB + 64*XSTR)
#define O_U   (O_CF + 5*CFSZ)             // union{ FB 8 rows+guard ; Hr 64x16 f32 }
#define O_XZ  (O_U + 2048)
#define O_GSH (O_XZ + 320)
#define O_BSH (O_GSH + 128)
#define O_W0T (O_BSH + 4*BSTR)
#define SMEM_HALFS (O_W0T + 8*W0STR + 24)

// ---------------------------------------------------------------------------
__global__ void prep(const float* __restrict__ W0, const float* __restrict__ W1,
                     const float* __restrict__ W2, _Float16* __restrict__ ws)
{
    int idx = blockIdx.x * 256 + threadIdx.x;
    if (idx >= WS_HALFS) return;
    float v = 0.f;
    if (idx < 4*S4) {
        int arr = idx / S4, e = idx % S4;
        int kc = e / (NMT*64*8); int r = e % (NMT*64*8);
        int mt = r / (64*8); r %= 64*8;
        int lane = r / 8, j = r % 8;
        int m = mt*16 + (lane & 15);
        int k = kc*32 + (lane >> 4)*8 + j;
        if (m < HID && k < HID) {
            if      (arr == 0) v = W1[k*HID + m];
            else if (arr == 1) v = W2[k*HID + m];
            else if (arr == 2) v = W1[m*HID + k];
            else               v = W2[m*HID + k];
        }
    } else if (idx < OFF_W0) {
        int e = idx - OFF_W0T;
        int mt = e / (64*8); int r = e % (64*8);
        int lane = r / 8, j = r % 8;
        int m = mt*16 + (lane & 15);
        int k = (lane >> 4)*8 + j;
        if (m < HID && k < ZD) v = W0[k*HID + m];
    } else {
        int e = idx - OFF_W0;
        int kc = e / (64*8); int r = e % (64*8);
        int lane = r / 8, j = r % 8;
        int m = (lane & 15);
        int k = kc*32 + (lane >> 4)*8 + j;
        if (k < HID) v = W0[m*HID + k];
    }
    ws[idx] = (_Float16)v;
}

// ---------------------------------------------------------------------------
__device__ __forceinline__ half4v pk4(float4v a) {
    half2v lo = __builtin_bit_cast(half2v, __builtin_amdgcn_cvt_pkrtz(a.x, a.y));
    half2v hi = __builtin_bit_cast(half2v, __builtin_amdgcn_cvt_pkrtz(a.z, a.w));
    return __builtin_shufflevector(lo, hi, 0, 1, 2, 3);
}
__device__ __forceinline__ void sig_sp(float x, float& sp, float& sg) {
    float e = __expf(-fabsf(x));
    float r = 1.0f / (1.0f + e);
    sg = (x >= 0.f) ? r : (1.0f - r);
    sp = fmaxf(x, 0.f) + __logf(1.f + e);
}

template<int NTILES>
__device__ __forceinline__ void run_mv(const half8* __restrict__ Asw,
                                       const _Float16* __restrict__ Xsrc,
                                       int mt0, int mtc, int lane,
                                       float4v acc[2][NTILES])
{
    const int lm = lane & 15, q = lane >> 4;
#pragma unroll
    for (int m = 0; m < 2; ++m)
#pragma unroll
        for (int n = 0; n < NTILES; ++n)
            acc[m][n] = (float4v){0.f, 0.f, 0.f, 0.f};
    for (int kc = 0; kc < NKC; ++kc) {
        half8 a[2];
#pragma unroll
        for (int m = 0; m < 2; ++m)
            if (m < mtc) a[m] = Asw[(kc*NMT + mt0 + m)*64 + lane];
        half8 x[NTILES];
#pragma unroll
        for (int n = 0; n < NTILES; ++n)
            x[n] = *(const half8*)(Xsrc + (n*16 + lm)*XSTR + kc*32 + q*8);
#pragma unroll
        for (int m = 0; m < 2; ++m)
            if (m < mtc)
#pragma unroll
                for (int n = 0; n < NTILES; ++n)
                    acc[m][n] = __builtin_amdgcn_mfma_f32_16x16x32_f16(a[m], x[n], acc[m][n], 0, 0, 0);
    }
}

// ---------------------------------------------------------------------------
__global__ void __launch_bounds__(NTHREADS, 4)   // 4 waves/EU -> VGPR<=128, 2 blocks/CU (LDS)
lnn_main(const float* __restrict__ z,
         const float* __restrict__ W0, const float* __restrict__ b0,
         const float* __restrict__ b1, const float* __restrict__ b2,
         const float* __restrict__ W3,
         const _Float16* __restrict__ ws,
         float* __restrict__ out)
{
    __shared__ alignas(16) _Float16 smem[SMEM_HALFS];
    _Float16* const Xt  = smem + O_XT;
    _Float16* const Xb  = smem + O_XB;
    _Float16* const Cf  = smem + O_CF;
    _Float16* const bsh = smem + O_BSH;
    _Float16* const w0t = smem + O_W0T;
    _Float16* const Xz  = smem + O_XZ;
    float*    const gsh = (float*)(smem + O_GSH);
    float*    const Hr  = (float*)(smem + O_U);
    _Float16* const FB  = smem + O_U;

    const int tid  = threadIdx.x;
    const int wave = tid >> 6;
    const int lane = tid & 63;
    const int lm   = lane & 15;
    const int q    = lane >> 4;
    const int sq   = lane & 7;
    const int tq   = (lane >> 3) & 1;
    const int s0   = blockIdx.x * BS;

    // T-phase: each wave owns 1-2 m-tiles x all 4 n-tiles
    const int mt0t = (wave < 5) ? wave*2 : (wave + 5);
    const int mtct = (wave < 5) ? 2 : 1;
    // F-phase: each wave owns up to 2 m-tiles (wave 7: none -> free for g-proj)
    const int mf0  = wave*2;
    const int mfc  = (wave < 6) ? 2 : ((wave == 6) ? 1 : 0);

    const half8* W1Tsw = (const half8*)(ws + OFF_W1T);
    const half8* W2Tsw = (const half8*)(ws + OFF_W2T);
    const half8* W1sw  = (const half8*)(ws + OFF_W1);
    const half8* W2sw  = (const half8*)(ws + OFF_W2);
    const half8* W0Tsw = (const half8*)(ws + OFF_W0T);
    const half8* W0sw  = (const half8*)(ws + OFF_W0);

    // ---- init/staging ----
    if (tid < 128) {
        int s = tid >> 4, k = tid & 15;
        Xz[s*40 + k]      = (_Float16)z[(s0 + s)*ZD + k];
        Xz[s*40 + 16 + k] = (_Float16)0.f;
    }
    for (int idx = tid; idx < 64*16; idx += NTHREADS) {
        int r = idx >> 4, c = 200 + (idx & 15);
        Xt[r*XSTR + c] = (_Float16)0.f;
        Xb[r*XSTR + c] = (_Float16)0.f;
    }
    for (int idx = tid; idx < 8*16; idx += NTHREADS) {
        int r = idx >> 4, c = 200 + (idx & 15);
        FB[r*XSTR + c] = (_Float16)0.f;
    }
    if (tid < 8) {
        Xt[64*XSTR + tid] = (_Float16)0.f;
        FB[8*XSTR + tid]  = (_Float16)0.f;
    }
    for (int idx = tid; idx < 4*BSTR; idx += NTHREADS) {
        int l = idx / BSTR, u = idx % BSTR;
        float v;
        if      (l == 0) v = b0[u];
        else if (l == 1) v = b1[u];
        else if (l == 2) v = b2[u];
        else             v = KSC * W3[u];
        bsh[idx] = (_Float16)v;
    }
    for (int idx = tid; idx < 8*W0STR + 24; idx += NTHREADS) {
        int t = idx / W0STR, u = idx % W0STR;
        w0t[idx] = (_Float16)((t < 8) ? SSC * W0[(DD + t)*HID + u] : 0.f);
    }
    __syncthreads();

    float4v acc1[2][1];
    float4v acc4[2][NT4];

    // ================= F0: a0 = z@W0+b0 -> FB, Cf0 =================
    if (mfc) {
        half8 xz = *(const half8*)(Xz + lm*40 + q*8);
#pragma unroll
        for (int m = 0; m < 2; ++m)
            if (m < mfc) {
                acc1[m][0] = (float4v){0.f,0.f,0.f,0.f};
                half8 aw = W0Tsw[(mf0 + m)*64 + lane];
                acc1[m][0] = __builtin_amdgcn_mfma_f32_16x16x32_f16(aw, xz, acc1[m][0], 0, 0, 0);
            }
        if (lm < 8)
#pragma unroll
            for (int m = 0; m < 2; ++m)
                if (m < mfc) {
                    const int ub = (mf0 + m)*16 + q*4;
                    half4v bb = *(const half4v*)(&bsh[0*BSTR + ub]);
                    float h[4], p[4];
#pragma unroll
                    for (int r = 0; r < 4; ++r) {
                        float av = acc1[m][0][r] + (float)bb[r];
                        sig_sp(av, h[r], p[r]);
                    }
                    *(half4v*)(&FB[lm*XSTR + ub])           = pk4((float4v){h[0],h[1],h[2],h[3]});
                    *(half4v*)(&Cf[0*CFSZ + lm*CSTR + ub])  = pk4((float4v){p[0],p[1],p[2],p[3]});
                }
    }
    __syncthreads();

    // ================= F1 =================
    if (mfc) run_mv<1>(W1Tsw, FB, mf0, mfc, lane, acc1);
    __syncthreads();
    if (mfc && lm < 8)
#pragma unroll
        for (int m = 0; m < 2; ++m)
            if (m < mfc) {
                const int ub = (mf0 + m)*16 + q*4;
                half4v bb = *(const half4v*)(&bsh[1*BSTR + ub]);
                float h[4], p[4];
#pragma unroll
                for (int r = 0; r < 4; ++r) {
                    float av = acc1[m][0][r] + (float)bb[r];
                    sig_sp(av, h[r], p[r]);
                }
                *(half4v*)(&FB[lm*XSTR + ub])          = pk4((float4v){h[0],h[1],h[2],h[3]});
                *(half4v*)(&Cf[1*CFSZ + lm*CSTR + ub]) = pk4((float4v){p[0],p[1],p[2],p[3]});
            }
    __syncthreads();

    // ========= P2: T2 (th0 on-the-fly) || F2 =========
    {
#pragma unroll
        for (int m = 0; m < 2; ++m)
#pragma unroll
            for (int n = 0; n < NT4; ++n)
                acc4[m][n] = (float4v){0.f, 0.f, 0.f, 0.f};
        for (int kc = 0; kc < NKC; ++kc) {
            half8 a[2];
#pragma unroll
            for (int m = 0; m < 2; ++m)
                if (m < mtct) a[m] = W1Tsw[(kc*NMT + mt0t + m)*64 + lane];
            half8 p0 = *(const half8*)(Cf + 0*CFSZ + sq*CSTR + kc*32 + q*8);
            half8 x[NT4];
#pragma unroll
            for (int n = 0; n < NT4; ++n) {
                int t = 2*n + tq;
                half8 w0 = *(const half8*)(w0t + t*W0STR + kc*32 + q*8);
                x[n] = p0 * w0;
            }
#pragma unroll
            for (int m = 0; m < 2; ++m)
                if (m < mtct)
#pragma unroll
                    for (int n = 0; n < NT4; ++n)
                        acc4[m][n] = __builtin_amdgcn_mfma_f32_16x16x32_f16(a[m], x[n], acc4[m][n], 0, 0, 0);
        }
        if (mfc) run_mv<1>(W2Tsw, FB, mf0, mfc, lane, acc1);
    }
    __syncthreads();
#pragma unroll
    for (int m = 0; m < 2; ++m)
        if (m < mtct) {
            const int ub = (mt0t + m)*16 + q*4;
            half4v p1 = *(const half4v*)(&Cf[1*CFSZ + sq*CSTR + ub]);
#pragma unroll
            for (int n = 0; n < NT4; ++n) {
                int row = n*16 + lm;
                *(half4v*)(&Xt[row*XSTR + ub]) = pk4(acc4[m][n]) * p1;
            }
        }
    if (mfc && lm < 8)
#pragma unroll
        for (int m = 0; m < 2; ++m)
            if (m < mfc) {
                const int ub = (mf0 + m)*16 + q*4;
                half4v bb = *(const half4v*)(&bsh[2*BSTR + ub]);
                half4v w3 = *(const half4v*)(&bsh[3*BSTR + ub]);
                float d2[4], c2[4];
#pragma unroll
                for (int r = 0; r < 4; ++r) {
                    float av = acc1[m][0][r] + (float)bb[r];
                    float e = __expf(-fabsf(av));
                    float rr = 1.f / (1.f + e);
                    float sg = (av >= 0.f) ? rr : (1.f - rr);
                    float wk = (float)w3[r];
                    d2[r] = wk * sg;
                    c2[r] = wk * sg * (1.f - sg);
                }
                *(half4v*)(&FB[lm*XSTR + ub])          = pk4((float4v){d2[0],d2[1],d2[2],d2[3]});
                *(half4v*)(&Cf[2*CFSZ + lm*CSTR + ub]) = pk4((float4v){c2[0],c2[1],c2[2],c2[3]});
            }
    __syncthreads();

    // ========= P3: T3 || B1 =========
    run_mv<NT4>(W2Tsw, Xt, mt0t, mtct, lane, acc4);
    if (mfc) run_mv<1>(W2sw, FB, mf0, mfc, lane, acc1);
    __syncthreads();
#pragma unroll
    for (int m = 0; m < 2; ++m)
        if (m < mtct) {
            const int ub = (mt0t + m)*16 + q*4;
            half4v c2 = *(const half4v*)(&Cf[2*CFSZ + sq*CSTR + ub]);
#pragma unroll
            for (int n = 0; n < NT4; ++n) {
                int row = n*16 + lm;
                *(half4v*)(&Xb[row*XSTR + ub]) = pk4(acc4[m][n]) * c2;
            }
        }
    if (mfc && lm < 8)
#pragma unroll
        for (int m = 0; m < 2; ++m)
            if (m < mfc) {
                const int ub = (mf0 + m)*16 + q*4;
                half4v p1 = *(const half4v*)(&Cf[1*CFSZ + lm*CSTR + ub]);
                half4v u1 = pk4(acc1[m][0]);
                half4v one = {(_Float16)1.f,(_Float16)1.f,(_Float16)1.f,(_Float16)1.f};
                *(half4v*)(&FB[lm*XSTR + ub])          = u1 * p1;
                *(half4v*)(&Cf[3*CFSZ + lm*CSTR + ub]) = u1 * (one - p1);
            }
    __syncthreads();

    // ========= P4: T4 || B0 =========
    run_mv<NT4>(W2sw, Xb, mt0t, mtct, lane, acc4);
    if (mfc) run_mv<1>(W1sw, FB, mf0, mfc, lane, acc1);
    __syncthreads();
#pragma unroll
    for (int m = 0; m < 2; ++m)
        if (m < mtct) {
            const int ub = (mt0t + m)*16 + q*4;
            half4v p1 = *(const half4v*)(&Cf[1*CFSZ + sq*CSTR + ub]);
            half4v c3 = *(const half4v*)(&Cf[3*CFSZ + sq*CSTR + ub]);
#pragma unroll
            for (int n = 0; n < NT4; ++n) {
                int row = n*16 + lm;
                half4v th1 = *(const half4v*)(&Xt[row*XSTR + ub]);
                *(half4v*)(&Xb[row*XSTR + ub]) = pk4(acc4[m][n]) * p1 + c3 * th1;
            }
        }
    if (mfc && lm < 8)
#pragma unroll
        for (int m = 0; m < 2; ++m)
            if (m < mfc) {
                const int ub = (mf0 + m)*16 + q*4;
                half4v p0 = *(const half4v*)(&Cf[0*CFSZ + lm*CSTR + ub]);
                half4v u0 = pk4(acc1[m][0]);
                half4v one = {(_Float16)1.f,(_Float16)1.f,(_Float16)1.f,(_Float16)1.f};
                half4v d0 = u0 * p0;
                *(half4v*)(&FB[lm*XSTR + ub])          = d0;
                *(half4v*)(&Cf[4*CFSZ + lm*CSTR + ub]) = d0 * (one - p0);
            }
    __syncthreads();

    // ========= P5: T5 || g-projection (wave 7: no F duty) =========
    run_mv<NT4>(W1sw, Xb, mt0t, mtct, lane, acc4);
    if (wave == 7) {
        float4v g = (float4v){0.f,0.f,0.f,0.f};
        for (int kc = 0; kc < NKC; ++kc) {
            half8 a = W0sw[kc*64 + lane];
            half8 x = *(const half8*)(FB + lm*XSTR + kc*32 + q*8);
            g = __builtin_amdgcn_mfma_f32_16x16x32_f16(a, x, g, 0, 0, 0);
        }
        if (q < 2 && lm < 8) {
            float4v gv;
            gv.x = g.x*INV_K; gv.y = g.y*INV_K; gv.z = g.z*INV_K; gv.w = g.w*INV_K;
            *(float4v*)(&gsh[lm*8 + q*4]) = gv;
        }
    }
#pragma unroll
    for (int m = 0; m < 2; ++m)
        if (m < mtct) {
            const int ub = (mt0t + m)*16 + q*4;
            half4v p0 = *(const half4v*)(&Cf[0*CFSZ + sq*CSTR + ub]);
            half4v c4 = *(const half4v*)(&Cf[4*CFSZ + sq*CSTR + ub]);
#pragma unroll
            for (int n = 0; n < NT4; ++n) {
                int row = n*16 + lm;
                int t = 2*n + tq;
                half4v w0 = *(const half4v*)(&w0t[t*W0STR + ub]);
                *(half4v*)(&Xt[row*XSTR + ub]) = pk4(acc4[m][n]) * p0 + c4 * w0;
            }
        }
    __syncthreads();

    // ========= P6: Hr projection (waves 0-3; FB region dead) =========
    if (wave < 4) {
        float4v hacc = (float4v){0.f,0.f,0.f,0.f};
        for (int kc = 0; kc < NKC; ++kc) {
            half8 a = W0sw[kc*64 + lane];
            half8 x = *(const half8*)(Xt + (wave*16 + lm)*XSTR + kc*32 + q*8);
            hacc = __builtin_amdgcn_mfma_f32_16x16x32_f16(a, x, hacc, 0, 0, 0);
        }
        int row = wave*16 + lm;
        float4v hv;
        hv.x = hacc.x*INV_KS; hv.y = hacc.y*INV_KS;
        hv.z = hacc.z*INV_KS; hv.w = hacc.w*INV_KS;
        *(float4v*)(&Hr[row*HSTR + q*4]) = hv;
    }
    __syncthreads();

    // ========= per-sample 8x8 solve (8 threads) =========
    if (tid < BS) {
        const int s = tid;
        float M[DD][DD], F[DD], v[DD], a[DD];
#pragma unroll
        for (int c = 0; c < DD; ++c) v[c] = z[(s0 + s)*ZD + DD + c];
#pragma unroll
        for (int r = 0; r < DD; ++r) {
            float f = gsh[s*8 + r];
#pragma unroll
            for (int c = 0; c < DD; ++c) {
                M[r][c] = Hr[(r*8 + s)*HSTR + DD + c] + ((r == c) ? 2.f*EPSL : 0.f);
                f -= Hr[(r*8 + s)*HSTR + c] * v[c];
            }
            F[r] = f;
        }
#pragma unroll
        for (int col = 0; col < DD; ++col) {
            const float inv = 1.f / M[col][col];
#pragma unroll
            for (int r = col + 1; r < DD; ++r) {
                const float fac = M[r][col] * inv;
#pragma unroll
                for (int c = col + 1; c < DD; ++c) M[r][c] -= fac * M[col][c];
                F[r] -= fac * F[col];
            }
        }
#pragma unroll
        for (int r = DD - 1; r >= 0; --r) {
            float ssum = F[r];
#pragma unroll
            for (int c = r + 1; c < DD; ++c) ssum -= M[r][c] * a[c];
            a[r] = ssum / M[r][r];
        }
        float* op = out + (size_t)(s0 + s)*ZD;
#pragma unroll
        for (int c = 0; c < DD; ++c) { op[c] = v[c]; op[DD + c] = a[c]; }
    }
}

extern "C" void kernel_launch(void* const* d_in, const int* in_sizes, int n_in,
                              void* d_out, int out_size, void* d_ws, size_t ws_size,
                              hipStream_t stream)
{
    const float* z  = (const float*)d_in[1];
    const float* W0 = (const float*)d_in[2];
    const float* b0 = (const float*)d_in[3];
    const float* W1 = (const float*)d_in[4];
    const float* b1 = (const float*)d_in[5];
    const float* W2 = (const float*)d_in[6];
    const float* b2 = (const float*)d_in[7];
    const float* W3 = (const float*)d_in[8];
    float* out = (float*)d_out;
    _Float16* ws = (_Float16*)d_ws;

    const int n = in_sizes[1] / (2*DD);

    prep<<<dim3((WS_HALFS + 255)/256), dim3(256), 0, stream>>>(W0, W1, W2, ws);
    lnn_main<<<dim3(n / BS), dim3(NTHREADS), 0, stream>>>(
        z, W0, b0, b1, b2, W3, ws, out);
}

// Round 4
// 166.755 us; speedup vs baseline: 1.4428x; 1.0207x over previous
//
#include <hip/hip_runtime.h>
#include <math.h>

#define DD 8
#define ZD 16
#define HID 200
#define EPSL 0.1f
#define BS 16          // samples per block
#define NTHREADS 1024  // 16 waves
#define NKC 7          // K chunks of 32 (200 -> 224)
#define NMT 13         // unit tiles of 16 (200 -> 208)
#define XSTR 216       // halfs per X row
#define CSTR 216       // halfs per coeff row
#define WSTR 208       // halfs per staged-weight row
#define HSTR 20        // floats per Hr row
#define NT4 2          // n-tiles per wave in T phase (4 n-groups x 2 tiles)

#define KSC 1024.0f
#define SSC 64.0f
#define INV_K (1.0f/1024.0f)
#define INV_KS (1.0f/65536.0f)

typedef _Float16 half8 __attribute__((ext_vector_type(8)));
typedef _Float16 half4v __attribute__((ext_vector_type(4)));
typedef _Float16 half2v __attribute__((ext_vector_type(2)));
typedef float float4v __attribute__((ext_vector_type(4)));

#define S4 (NKC*NMT*64*8)
#define OFF_W1T 0
#define OFF_W2T (S4)
#define OFF_W1  (2*S4)
#define OFF_W2  (3*S4)
#define OFF_W0T (4*S4)
#define OFF_W0  (4*S4 + NMT*64*8)
#define WS_HALFS (4*S4 + NMT*64*8 + NKC*64*8)

// ---- LDS layout (units: _Float16) ----
#define CFSZ  (16*CSTR)
#define O_XT  0                          // Xt: 128 rows + 8-half guard
#define O_XB  (128*XSTR + 8)             // Xb: 128 rows (overflow -> Cf0 row0, finite)
#define O_CF  (O_XB + 128*XSTR)          // Cf[5]
#define O_BSH (O_CF + 5*CFSZ)            // b0,b1,b2,KSC*W3
#define O_W0T (O_BSH + 4*WSTR)           // SSC*W0[8+t][u] + 24-half guard
#define O_XZ  (O_W0T + 8*WSTR + 24)      // z staging 16x40
#define O_GSH (O_XZ + 16*40)             // 16x8 f32
#define O_HR  (O_GSH + 256)              // union{ Hr 128x20 f32 ; FB 16 rows + guard }
#define SMEM_HALFS (O_HR + 128*HSTR*2)

// ---------------------------------------------------------------------------
__global__ void prep(const float* __restrict__ W0, const float* __restrict__ W1,
                     const float* __restrict__ W2, _Float16* __restrict__ ws)
{
    int idx = blockIdx.x * 256 + threadIdx.x;
    if (idx >= WS_HALFS) return;
    float v = 0.f;
    if (idx < 4*S4) {
        int arr = idx / S4, e = idx % S4;
        int kc = e / (NMT*64*8); int r = e % (NMT*64*8);
        int mt = r / (64*8); r %= 64*8;
        int lane = r / 8, j = r % 8;
        int m = mt*16 + (lane & 15);
        int k = kc*32 + (lane >> 4)*8 + j;
        if (m < HID && k < HID) {
            if      (arr == 0) v = W1[k*HID + m];
            else if (arr == 1) v = W2[k*HID + m];
            else if (arr == 2) v = W1[m*HID + k];
            else               v = W2[m*HID + k];
        }
    } else if (idx < OFF_W0) {
        int e = idx - OFF_W0T;
        int mt = e / (64*8); int r = e % (64*8);
        int lane = r / 8, j = r % 8;
        int m = mt*16 + (lane & 15);
        int k = (lane >> 4)*8 + j;
        if (m < HID && k < ZD) v = W0[k*HID + m];
    } else {
        int e = idx - OFF_W0;
        int kc = e / (64*8); int r = e % (64*8);
        int lane = r / 8, j = r % 8;
        int m = (lane & 15);
        int k = kc*32 + (lane >> 4)*8 + j;
        if (k < HID) v = W0[m*HID + k];
    }
    ws[idx] = (_Float16)v;
}

// ---------------------------------------------------------------------------
__device__ __forceinline__ half4v pk4(float4v a) {
    half2v lo = __builtin_bit_cast(half2v, __builtin_amdgcn_cvt_pkrtz(a.x, a.y));
    half2v hi = __builtin_bit_cast(half2v, __builtin_amdgcn_cvt_pkrtz(a.z, a.w));
    return __builtin_shufflevector(lo, hi, 0, 1, 2, 3);
}
__device__ __forceinline__ void sig_sp(float x, float& sp, float& sg) {
    float e = __expf(-fabsf(x));
    float r = 1.0f / (1.0f + e);
    sg = (x >= 0.f) ? r : (1.0f - r);
    sp = fmaxf(x, 0.f) + __logf(1.f + e);
}

template<int MT, int NT>
__device__ __forceinline__ void run_mv(const half8* __restrict__ Asw,
                                       const _Float16* __restrict__ Xsrc,
                                       int mt0, int mtc, int lane,
                                       float4v acc[MT][NT])
{
    const int lm = lane & 15, q = lane >> 4;
#pragma unroll
    for (int m = 0; m < MT; ++m)
#pragma unroll
        for (int n = 0; n < NT; ++n)
            acc[m][n] = (float4v){0.f, 0.f, 0.f, 0.f};
    for (int kc = 0; kc < NKC; ++kc) {
        half8 a[MT];
#pragma unroll
        for (int m = 0; m < MT; ++m)
            if (m < mtc) a[m] = Asw[(kc*NMT + mt0 + m)*64 + lane];
        half8 x[NT];
#pragma unroll
        for (int n = 0; n < NT; ++n)
            x[n] = *(const half8*)(Xsrc + (n*16 + lm)*XSTR + kc*32 + q*8);
#pragma unroll
        for (int m = 0; m < MT; ++m)
            if (m < mtc)
#pragma unroll
                for (int n = 0; n < NT; ++n)
                    acc[m][n] = __builtin_amdgcn_mfma_f32_16x16x32_f16(a[m], x[n], acc[m][n], 0, 0, 0);
    }
}

// ---------------------------------------------------------------------------
__global__ void __launch_bounds__(NTHREADS, 4)
lnn_main(const float* __restrict__ z,
         const float* __restrict__ W0, const float* __restrict__ b0,
         const float* __restrict__ b1, const float* __restrict__ b2,
         const float* __restrict__ W3,
         const _Float16* __restrict__ ws,
         float* __restrict__ out)
{
    __shared__ alignas(16) _Float16 smem[SMEM_HALFS];
    _Float16* const Xt  = smem + O_XT;
    _Float16* const Xb  = smem + O_XB;
    _Float16* const Cf  = smem + O_CF;   // Cf + j*CFSZ
    _Float16* const bsh = smem + O_BSH;
    _Float16* const w0t = smem + O_W0T;
    _Float16* const Xz  = smem + O_XZ;
    float*    const gsh = (float*)(smem + O_GSH);
    float*    const Hr  = (float*)(smem + O_HR);
    _Float16* const FB  = smem + O_HR;   // F/B 16-row chain, dead before Hr written

    const int tid  = threadIdx.x;
    const int wave = tid >> 6;
    const int lane = tid & 63;
    const int lm   = lane & 15;
    const int q    = lane >> 4;
    const int s0   = blockIdx.x * BS;

    // T-phase wave grid: 4 m-groups x 4 n-groups (mtct<=4, 2 n-tiles each)
    // X-read duplication = 4 (was 8): LDS traffic halved; A comes from global/L2.
    const int ng   = wave & 3;
    const int mg   = wave >> 2;
    const int mt0t = mg * 4;
    const int mtct = (mg < 3) ? 4 : 1;   // group 3 owns tile 12 only

    const half8* W1Tsw = (const half8*)(ws + OFF_W1T);
    const half8* W2Tsw = (const half8*)(ws + OFF_W2T);
    const half8* W1sw  = (const half8*)(ws + OFF_W1);
    const half8* W2sw  = (const half8*)(ws + OFF_W2);
    const half8* W0Tsw = (const half8*)(ws + OFF_W0T);
    const half8* W0sw  = (const half8*)(ws + OFF_W0);

    // ---- init/staging ----
    if (tid < 256) {
        int s = tid >> 4, k = tid & 15;
        Xz[s*40 + k]      = (_Float16)z[(s0 + s)*ZD + k];
        Xz[s*40 + 16 + k] = (_Float16)0.f;
    }
    for (int idx = tid; idx < 128*16; idx += NTHREADS) {
        int r = idx >> 4, c = 200 + (idx & 15);
        Xt[r*XSTR + c] = (_Float16)0.f;
        Xb[r*XSTR + c] = (_Float16)0.f;
    }
    for (int idx = tid; idx < 16*16; idx += NTHREADS) {
        int r = idx >> 4, c = 200 + (idx & 15);
        FB[r*XSTR + c] = (_Float16)0.f;
    }
    if (tid < 8) {
        Xt[128*XSTR + tid] = (_Float16)0.f;  // Xt row-127 kc6/q3 overflow guard
        FB[16*XSTR + tid]  = (_Float16)0.f;  // FB row-15 overflow guard
    }
    for (int idx = tid; idx < 5*16*8; idx += NTHREADS) {
        int j = idx >> 7, r = (idx >> 3) & 15, c = 208 + (idx & 7);
        Cf[j*CFSZ + r*CSTR + c] = (_Float16)0.f;  // half8-read tail of Cf rows
    }
    for (int idx = tid; idx < 4*WSTR; idx += NTHREADS) {
        int l = idx / WSTR, u = idx % WSTR;
        float v = 0.f;
        if (u < HID) {
            if      (l == 0) v = b0[u];
            else if (l == 1) v = b1[u];
            else if (l == 2) v = b2[u];
            else             v = KSC * W3[u];
        }
        bsh[idx] = (_Float16)v;
    }
    for (int idx = tid; idx < 8*WSTR + 24; idx += NTHREADS) {
        int t = idx / WSTR, u = idx % WSTR;
        w0t[idx] = (_Float16)((t < 8 && u < HID) ? SSC * W0[(DD + t)*HID + u] : 0.f);
    }
    __syncthreads();

    float4v acc1[1][1];
    float4v acc4[4][NT4];
    const int ubf = wave*16 + q*4;   // F-duty unit base (wave<13)

    // ================= F0: a0 = z@W0+b0 -> FB, Cf0 =================
    if (wave < NMT) {
        acc1[0][0] = (float4v){0.f,0.f,0.f,0.f};
        half8 xz = *(const half8*)(Xz + lm*40 + q*8);
        half8 aw = W0Tsw[wave*64 + lane];
        acc1[0][0] = __builtin_amdgcn_mfma_f32_16x16x32_f16(aw, xz, acc1[0][0], 0, 0, 0);
        half4v bb = *(const half4v*)(&bsh[0*WSTR + ubf]);
        float h[4], p[4];
#pragma unroll
        for (int r = 0; r < 4; ++r) {
            float av = acc1[0][0][r] + (float)bb[r];
            sig_sp(av, h[r], p[r]);
        }
        *(half4v*)(&FB[lm*XSTR + ubf])          = pk4((float4v){h[0],h[1],h[2],h[3]});
        *(half4v*)(&Cf[0*CFSZ + lm*CSTR + ubf]) = pk4((float4v){p[0],p[1],p[2],p[3]});
    }
    __syncthreads();

    // ================= F1 =================
    if (wave < NMT) run_mv<1,1>(W1Tsw, FB, wave, 1, lane, acc1);
    __syncthreads();
    if (wave < NMT) {
        half4v bb = *(const half4v*)(&bsh[1*WSTR + ubf]);
        float h[4], p[4];
#pragma unroll
        for (int r = 0; r < 4; ++r) {
            float av = acc1[0][0][r] + (float)bb[r];
            sig_sp(av, h[r], p[r]);
        }
        *(half4v*)(&FB[lm*XSTR + ubf])          = pk4((float4v){h[0],h[1],h[2],h[3]});
        *(half4v*)(&Cf[1*CFSZ + lm*CSTR + ubf]) = pk4((float4v){p[0],p[1],p[2],p[3]});
    }
    __syncthreads();

    // ========= P2: T2 (th0 on-the-fly) || F2 =========
    {
#pragma unroll
        for (int m = 0; m < 4; ++m)
#pragma unroll
            for (int n = 0; n < NT4; ++n)
                acc4[m][n] = (float4v){0.f, 0.f, 0.f, 0.f};
        for (int kc = 0; kc < NKC; ++kc) {
            half8 a[4];
#pragma unroll
            for (int m = 0; m < 4; ++m)
                if (m < mtct) a[m] = W1Tsw[(kc*NMT + mt0t + m)*64 + lane];
            half8 p0 = *(const half8*)(Cf + 0*CFSZ + lm*CSTR + kc*32 + q*8);
            half8 x[NT4];
#pragma unroll
            for (int n = 0; n < NT4; ++n) {
                half8 w0 = *(const half8*)(w0t + (ng*NT4 + n)*WSTR + kc*32 + q*8);
                x[n] = p0 * w0;   // th0 = p0 .* (S*W0row), generated in-register
            }
#pragma unroll
            for (int m = 0; m < 4; ++m)
                if (m < mtct)
#pragma unroll
                    for (int n = 0; n < NT4; ++n)
                        acc4[m][n] = __builtin_amdgcn_mfma_f32_16x16x32_f16(a[m], x[n], acc4[m][n], 0, 0, 0);
        }
        if (wave < NMT) run_mv<1,1>(W2Tsw, FB, wave, 1, lane, acc1);
    }
    __syncthreads();
#pragma unroll
    for (int m = 0; m < 4; ++m)
        if (m < mtct) {
            const int ub = (mt0t + m)*16 + q*4;
            half4v p1 = *(const half4v*)(&Cf[1*CFSZ + lm*CSTR + ub]);
#pragma unroll
            for (int n = 0; n < NT4; ++n) {
                int row = (ng*NT4 + n)*16 + lm;
                *(half4v*)(&Xt[row*XSTR + ub]) = pk4(acc4[m][n]) * p1;
            }
        }
    if (wave < NMT) {  // F2 epi: d2'=K*w3*sg -> FB, c2'=K*w3*sg(1-sg) -> Cf2
        half4v bb = *(const half4v*)(&bsh[2*WSTR + ubf]);
        half4v w3 = *(const half4v*)(&bsh[3*WSTR + ubf]);
        float d2[4], c2[4];
#pragma unroll
        for (int r = 0; r < 4; ++r) {
            float av = acc1[0][0][r] + (float)bb[r];
            float e = __expf(-fabsf(av));
            float rr = 1.f / (1.f + e);
            float sg = (av >= 0.f) ? rr : (1.f - rr);
            float wk = (float)w3[r];
            d2[r] = wk * sg;
            c2[r] = wk * sg * (1.f - sg);
        }
        *(half4v*)(&FB[lm*XSTR + ubf])          = pk4((float4v){d2[0],d2[1],d2[2],d2[3]});
        *(half4v*)(&Cf[2*CFSZ + lm*CSTR + ubf]) = pk4((float4v){c2[0],c2[1],c2[2],c2[3]});
    }
    __syncthreads();

    // ========= P3: T3 || B1 =========
    run_mv<4,NT4>(W2Tsw, Xt + ng*32*XSTR, mt0t, mtct, lane, acc4);
    if (wave < NMT) run_mv<1,1>(W2sw, FB, wave, 1, lane, acc1);
    __syncthreads();
#pragma unroll
    for (int m = 0; m < 4; ++m)
        if (m < mtct) {
            const int ub = (mt0t + m)*16 + q*4;
            half4v c2 = *(const half4v*)(&Cf[2*CFSZ + lm*CSTR + ub]);
#pragma unroll
            for (int n = 0; n < NT4; ++n) {
                int row = (ng*NT4 + n)*16 + lm;
                *(half4v*)(&Xb[row*XSTR + ub]) = pk4(acc4[m][n]) * c2;
            }
        }
    if (wave < NMT) {  // B1 epi
        half4v p1 = *(const half4v*)(&Cf[1*CFSZ + lm*CSTR + ubf]);
        half4v u1 = pk4(acc1[0][0]);
        half4v one = {(_Float16)1.f,(_Float16)1.f,(_Float16)1.f,(_Float16)1.f};
        *(half4v*)(&FB[lm*XSTR + ubf])          = u1 * p1;
        *(half4v*)(&Cf[3*CFSZ + lm*CSTR + ubf]) = u1 * (one - p1);
    }
    __syncthreads();

    // ========= P4: T4 || B0 =========
    run_mv<4,NT4>(W2sw, Xb + ng*32*XSTR, mt0t, mtct, lane, acc4);
    if (wave < NMT) run_mv<1,1>(W1sw, FB, wave, 1, lane, acc1);
    __syncthreads();
#pragma unroll
    for (int m = 0; m < 4; ++m)
        if (m < mtct) {
            const int ub = (mt0t + m)*16 + q*4;
            half4v p1 = *(const half4v*)(&Cf[1*CFSZ + lm*CSTR + ub]);
            half4v c3 = *(const half4v*)(&Cf[3*CFSZ + lm*CSTR + ub]);
#pragma unroll
            for (int n = 0; n < NT4; ++n) {
                int row = (ng*NT4 + n)*16 + lm;
                half4v th1 = *(const half4v*)(&Xt[row*XSTR + ub]);
                *(half4v*)(&Xb[row*XSTR + ub]) = pk4(acc4[m][n]) * p1 + c3 * th1;
            }
        }
    if (wave < NMT) {  // B0 epi
        half4v p0 = *(const half4v*)(&Cf[0*CFSZ + lm*CSTR + ubf]);
        half4v u0 = pk4(acc1[0][0]);
        half4v one = {(_Float16)1.f,(_Float16)1.f,(_Float16)1.f,(_Float16)1.f};
        half4v d0 = u0 * p0;
        *(half4v*)(&FB[lm*XSTR + ubf])          = d0;
        *(half4v*)(&Cf[4*CFSZ + lm*CSTR + ubf]) = d0 * (one - p0);
    }
    __syncthreads();

    // ========= P5: T5 || g-projection; epilogue needs no mid-barrier =========
    run_mv<4,NT4>(W1sw, Xb + ng*32*XSTR, mt0t, mtct, lane, acc4);
    if (wave == 13) {   // g = W0 d0'
        float4v g = (float4v){0.f,0.f,0.f,0.f};
        for (int kc = 0; kc < NKC; ++kc) {
            half8 a = W0sw[kc*64 + lane];
            half8 x = *(const half8*)(FB + lm*XSTR + kc*32 + q*8);
            g = __builtin_amdgcn_mfma_f32_16x16x32_f16(a, x, g, 0, 0, 0);
        }
        if (q < 2) {
            float4v gv;
            gv.x = g.x*INV_K; gv.y = g.y*INV_K; gv.z = g.z*INV_K; gv.w = g.w*INV_K;
            *(float4v*)(&gsh[lm*8 + q*4]) = gv;
        }
    }
#pragma unroll
    for (int m = 0; m < 4; ++m)
        if (m < mtct) {
            const int ub = (mt0t + m)*16 + q*4;
            half4v p0 = *(const half4v*)(&Cf[0*CFSZ + lm*CSTR + ub]);
            half4v c4 = *(const half4v*)(&Cf[4*CFSZ + lm*CSTR + ub]);
#pragma unroll
            for (int n = 0; n < NT4; ++n) {
                int row = (ng*NT4 + n)*16 + lm;
                half4v w0 = *(const half4v*)(&w0t[(ng*NT4 + n)*WSTR + ub]);
                *(half4v*)(&Xt[row*XSTR + ub]) = pk4(acc4[m][n]) * p0 + c4 * w0;
            }
        }
    __syncthreads();

    // ========= P6: Hr projection (waves 0-7; clobbers FB region -- FB is dead) =========
    if (wave < 8) {
        float4v hacc = (float4v){0.f,0.f,0.f,0.f};
        for (int kc = 0; kc < NKC; ++kc) {
            half8 a = W0sw[kc*64 + lane];
            half8 x = *(const half8*)(Xt + (wave*16 + lm)*XSTR + kc*32 + q*8);
            hacc = __builtin_amdgcn_mfma_f32_16x16x32_f16(a, x, hacc, 0, 0, 0);
        }
        int row = wave*16 + lm;
        float4v hv;
        hv.x = hacc.x*INV_KS; hv.y = hacc.y*INV_KS;
        hv.z = hacc.z*INV_KS; hv.w = hacc.w*INV_KS;
        *(float4v*)(&Hr[row*HSTR + q*4]) = hv;
    }
    __syncthreads();

    // ========= per-sample 8x8 solve =========
    if (tid < BS) {
        const int s = tid;
        float M[DD][DD], F[DD], v[DD], a[DD];
#pragma unroll
        for (int c = 0; c < DD; ++c) v[c] = z[(s0 + s)*ZD + DD + c];
#pragma unroll
        for (int r = 0; r < DD; ++r) {
            float f = gsh[s*8 + r];
#pragma unroll
            for (int c = 0; c < DD; ++c) {
                M[r][c] = Hr[(r*16 + s)*HSTR + DD + c] + ((r == c) ? 2.f*EPSL : 0.f);
                f -= Hr[(r*16 + s)*HSTR + c] * v[c];
            }
            F[r] = f;
        }
#pragma unroll
        for (int col = 0; col < DD; ++col) {
            const float inv = 1.f / M[col][col];
#pragma unroll
            for (int r = col + 1; r < DD; ++r) {
                const float fac = M[r][col] * inv;
#pragma unroll
                for (int c = col + 1; c < DD; ++c) M[r][c] -= fac * M[col][c];
                F[r] -= fac * F[col];
            }
        }
#pragma unroll
        for (int r = DD - 1; r >= 0; --r) {
            float ssum = F[r];
#pragma unroll
            for (int c = r + 1; c < DD; ++c) ssum -= M[r][c] * a[c];
            a[r] = ssum / M[r][r];
        }
        float* op = out + (size_t)(s0 + s)*ZD;
#pragma unroll
        for (int c = 0; c < DD; ++c) { op[c] = v[c]; op[DD + c] = a[c]; }
    }
}

extern "C" void kernel_launch(void* const* d_in, const int* in_sizes, int n_in,
                              void* d_out, int out_size, void* d_ws, size_t ws_size,
                              hipStream_t stream)
{
    const float* z  = (const float*)d_in[1];
    const float* W0 = (const float*)d_in[2];
    const float* b0 = (const float*)d_in[3];
    const float* W1 = (const float*)d_in[4];
    const float* b1 = (const float*)d_in[5];
    const float* W2 = (const float*)d_in[6];
    const float* b2 = (const float*)d_in[7];
    const float* W3 = (const float*)d_in[8];
    float* out = (float*)d_out;
    _Float16* ws = (_Float16*)d_ws;

    const int n = in_sizes[1] / (2*DD);

    prep<<<dim3((WS_HALFS + 255)/256), dim3(256), 0, stream>>>(W0, W1, W2, ws);
    lnn_main<<<dim3(n / BS), dim3(NTHREADS), 0, stream>>>(
        z, W0, b0, b1, b2, W3, ws, out);
}

// Round 5
// 157.534 us; speedup vs baseline: 1.5272x; 1.0585x over previous
//
#include <hip/hip_runtime.h>
#include <math.h>

#define DD 8
#define ZD 16
#define HID 200
#define EPSL 0.1f
#define BS 16          // samples per block
#define NTHREADS 1024  // 16 waves
#define NKC 7          // K chunks of 32 (200 -> 224)
#define NMT 13         // unit tiles of 16 (200 -> 208)
#define XSTR 216       // halfs per X row (432B: 2-way-free, 16B-aligned)
#define CSTR 208       // halfs per coeff row
#define FBSTR 200      // halfs per F-chain row (400B: 2-way-free)
#define WSTR 208       // halfs per staged-weight row
#define HSTR 20        // floats per Hr row
#define NT4 4          // n-tiles per wave in T phase

#define KSC 1024.0f
#define SSC 64.0f
#define INV_K (1.0f/1024.0f)
#define INV_KS (1.0f/65536.0f)

typedef _Float16 half8 __attribute__((ext_vector_type(8)));
typedef _Float16 half4v __attribute__((ext_vector_type(4)));
typedef _Float16 half2v __attribute__((ext_vector_type(2)));
typedef float float4v __attribute__((ext_vector_type(4)));

#define S4 (NKC*NMT*64*8)
#define OFF_W1T 0
#define OFF_W2T (S4)
#define OFF_W1  (2*S4)
#define OFF_W2  (3*S4)
#define OFF_W0T (4*S4)
#define OFF_W0  (4*S4 + NMT*64*8)
#define WS_HALFS (4*S4 + NMT*64*8 + NKC*64*8)

// ---- LDS layout (units: _Float16). Total 81176 halfs = 162352 B ----
#define CFSZ  (16*CSTR)
#define O_XT  0                              // Xt 128 rows + 8 guard
#define O_XB  (128*XSTR + 8)                 // Xb 128 rows + 8 guard (hosts Hr in P6+)
#define O_CF  (O_XB + 128*XSTR + 8)          // Cf[5]
#define O_FBA (O_CF + 5*CFSZ)                // F-chain ping A: 16x200 + 24 guard
#define O_FBB (O_FBA + 16*FBSTR + 24)        // F-chain ping B
#define O_BSH (O_FBB + 16*FBSTR + 24)        // b0,b1,b2,KSC*W3
#define O_W0T (O_BSH + 4*WSTR)               // SSC*W0[8+t][u] + 24 guard
#define O_GSH (O_W0T + 8*WSTR + 24)          // 16x8 f32
#define SMEM_HALFS (O_GSH + 256)

// ---------------------------------------------------------------------------
__global__ void prep(const float* __restrict__ W0, const float* __restrict__ W1,
                     const float* __restrict__ W2, _Float16* __restrict__ ws)
{
    int idx = blockIdx.x * 256 + threadIdx.x;
    if (idx >= WS_HALFS) return;
    float v = 0.f;
    if (idx < 4*S4) {
        int arr = idx / S4, e = idx % S4;
        int kc = e / (NMT*64*8); int r = e % (NMT*64*8);
        int mt = r / (64*8); r %= 64*8;
        int lane = r / 8, j = r % 8;
        int m = mt*16 + (lane & 15);
        int k = kc*32 + (lane >> 4)*8 + j;
        if (m < HID && k < HID) {
            if      (arr == 0) v = W1[k*HID + m];
            else if (arr == 1) v = W2[k*HID + m];
            else if (arr == 2) v = W1[m*HID + k];
            else               v = W2[m*HID + k];
        }
    } else if (idx < OFF_W0) {
        int e = idx - OFF_W0T;
        int mt = e / (64*8); int r = e % (64*8);
        int lane = r / 8, j = r % 8;
        int m = mt*16 + (lane & 15);
        int k = (lane >> 4)*8 + j;
        if (m < HID && k < ZD) v = W0[k*HID + m];
    } else {
        int e = idx - OFF_W0;
        int kc = e / (64*8); int r = e % (64*8);
        int lane = r / 8, j = r % 8;
        int m = (lane & 15);
        int k = kc*32 + (lane >> 4)*8 + j;
        if (k < HID) v = W0[m*HID + k];
    }
    ws[idx] = (_Float16)v;
}

// ---------------------------------------------------------------------------
__device__ __forceinline__ half4v pk4(float4v a) {
    half2v lo = __builtin_bit_cast(half2v, __builtin_amdgcn_cvt_pkrtz(a.x, a.y));
    half2v hi = __builtin_bit_cast(half2v, __builtin_amdgcn_cvt_pkrtz(a.z, a.w));
    return __builtin_shufflevector(lo, hi, 0, 1, 2, 3);
}
__device__ __forceinline__ void sig_sp(float x, float& sp, float& sg) {
    float e = __expf(-fabsf(x));
    float r = 1.0f / (1.0f + e);
    sg = (x >= 0.f) ? r : (1.0f - r);
    sp = fmaxf(x, 0.f) + __logf(1.f + e);
}

template<int MT, int NT, int STR>
__device__ __forceinline__ void run_mv(const half8* __restrict__ Asw,
                                       const _Float16* __restrict__ Xsrc,
                                       int mt0, int mtc, int lane,
                                       float4v acc[MT][NT])
{
    const int lm = lane & 15, q = lane >> 4;
#pragma unroll
    for (int m = 0; m < MT; ++m)
#pragma unroll
        for (int n = 0; n < NT; ++n)
            acc[m][n] = (float4v){0.f, 0.f, 0.f, 0.f};
    for (int kc = 0; kc < NKC; ++kc) {
        half8 a[MT];
#pragma unroll
        for (int m = 0; m < MT; ++m)
            if (m < mtc) a[m] = Asw[(kc*NMT + mt0 + m)*64 + lane];
        half8 x[NT];
#pragma unroll
        for (int n = 0; n < NT; ++n)
            x[n] = *(const half8*)(Xsrc + (n*16 + lm)*STR + kc*32 + q*8);
#pragma unroll
        for (int m = 0; m < MT; ++m)
            if (m < mtc)
#pragma unroll
                for (int n = 0; n < NT; ++n)
                    acc[m][n] = __builtin_amdgcn_mfma_f32_16x16x32_f16(a[m], x[n], acc[m][n], 0, 0, 0);
    }
}

// T-main with x = src-row ⊙ coeff-row (coeff broadcast over n)
template<int NT>
__device__ __forceinline__ void run_mv_mod(const half8* __restrict__ Asw,
                                           const _Float16* __restrict__ Xsrc,
                                           const _Float16* __restrict__ crow,
                                           int mt0, int mtc, int lane,
                                           float4v acc[2][NT])
{
    const int lm = lane & 15, q = lane >> 4;
#pragma unroll
    for (int m = 0; m < 2; ++m)
#pragma unroll
        for (int n = 0; n < NT; ++n)
            acc[m][n] = (float4v){0.f, 0.f, 0.f, 0.f};
    for (int kc = 0; kc < NKC; ++kc) {
        half8 a[2];
#pragma unroll
        for (int m = 0; m < 2; ++m)
            if (m < mtc) a[m] = Asw[(kc*NMT + mt0 + m)*64 + lane];
        half8 cm = *(const half8*)(crow + kc*32 + q*8);
        half8 x[NT];
#pragma unroll
        for (int n = 0; n < NT; ++n) {
            half8 xv = *(const half8*)(Xsrc + (n*16 + lm)*XSTR + kc*32 + q*8);
            x[n] = xv * cm;
        }
#pragma unroll
        for (int m = 0; m < 2; ++m)
            if (m < mtc)
#pragma unroll
                for (int n = 0; n < NT; ++n)
                    acc[m][n] = __builtin_amdgcn_mfma_f32_16x16x32_f16(a[m], x[n], acc[m][n], 0, 0, 0);
    }
}

// ---------------------------------------------------------------------------
__global__ void __launch_bounds__(NTHREADS, 4)
lnn_main(const float* __restrict__ z,
         const float* __restrict__ W0, const float* __restrict__ b0,
         const float* __restrict__ b1, const float* __restrict__ b2,
         const float* __restrict__ W3,
         const _Float16* __restrict__ ws,
         float* __restrict__ out)
{
    __shared__ alignas(16) _Float16 smem[SMEM_HALFS];
    _Float16* const Xt  = smem + O_XT;
    _Float16* const Xb  = smem + O_XB;
    _Float16* const Cf  = smem + O_CF;
    _Float16* const FBa = smem + O_FBA;
    _Float16* const FBb = smem + O_FBB;
    _Float16* const bsh = smem + O_BSH;
    _Float16* const w0t = smem + O_W0T;
    float*    const gsh = (float*)(smem + O_GSH);
    float*    const Hr  = (float*)(smem + O_XB);  // overlay; Xb dead after T5main

    const int tid  = threadIdx.x;
    const int wave = tid >> 6;
    const int lane = tid & 63;
    const int lm   = lane & 15;
    const int q    = lane >> 4;
    const int s0   = blockIdx.x * BS;

    // T-phase wave grid: 8 m-groups x 2 n-groups
    const int twm  = wave >> 1;
    const int twn  = wave & 1;
    const int mt0t = (twm < 5) ? twm*2 : (twm + 5);
    const int mtct = (twm < 5) ? 2 : 1;

    const half8* W1Tsw = (const half8*)(ws + OFF_W1T);
    const half8* W2Tsw = (const half8*)(ws + OFF_W2T);
    const half8* W1sw  = (const half8*)(ws + OFF_W1);
    const half8* W2sw  = (const half8*)(ws + OFF_W2);
    const half8* W0Tsw = (const half8*)(ws + OFF_W0T);
    const half8* W0sw  = (const half8*)(ws + OFF_W0);

    const int ubf = wave*16 + q*4;   // F-duty unit base (wave<13)
    const half4v one = {(_Float16)1.f,(_Float16)1.f,(_Float16)1.f,(_Float16)1.f};

    float4v acc1[1][1];
    float4v acc4[2][NT4];

    // ---- init staging (no Xz; F0 reads globals directly) ----
    for (int idx = tid; idx < 128*16; idx += NTHREADS) {
        int r = idx >> 4, c = 200 + (idx & 15);
        Xt[r*XSTR + c] = (_Float16)0.f;
        Xb[r*XSTR + c] = (_Float16)0.f;
    }
    if (tid < 8) {
        Xt[128*XSTR + tid] = (_Float16)0.f;   // row-127 kc6 overflow guard
        Xb[128*XSTR + tid] = (_Float16)0.f;
    }
    if (tid >= 32 && tid < 80) {             // FBa/FBb tail guards (24 each)
        int t = tid - 32;
        if (t < 24) FBa[16*FBSTR + t] = (_Float16)0.f;
        else        FBb[16*FBSTR + (t-24)] = (_Float16)0.f;
    }
    if (tid >= 128 && tid < 176) {           // Cf1..Cf3 row0 cols0-15 (benign-race landing pads)
        int t = tid - 128;                   // 48 halfs
        int j = 1 + t/16, c = t & 15;
        Cf[j*CFSZ + c] = (_Float16)0.f;
    }
    for (int idx = tid; idx < 4*WSTR; idx += NTHREADS) {
        int l = idx / WSTR, u = idx % WSTR;
        float v = 0.f;
        if (u < HID) {
            if      (l == 0) v = b0[u];
            else if (l == 1) v = b1[u];
            else if (l == 2) v = b2[u];
            else             v = KSC * W3[u];
        }
        bsh[idx] = (_Float16)v;
    }
    for (int idx = tid; idx < 8*WSTR + 24; idx += NTHREADS) {
        int t = idx / WSTR, u = idx % WSTR;
        w0t[idx] = (_Float16)((t < 8 && u < HID) ? SSC * W0[(DD + t)*HID + u] : 0.f);
    }

    // ---- F0 (concurrent with staging: reads only globals) ----
    if (wave < NMT) {
        half8 xz;
#pragma unroll
        for (int j = 0; j < 8; ++j) xz[j] = (_Float16)0.f;
        if (q < 2) {
            const float* zp = z + (size_t)(s0 + lm)*ZD + q*8;
#pragma unroll
            for (int j = 0; j < 8; ++j) xz[j] = (_Float16)zp[j];  // RNE, matches R1 staging
        }
        acc1[0][0] = (float4v){0.f,0.f,0.f,0.f};
        half8 aw = W0Tsw[wave*64 + lane];
        acc1[0][0] = __builtin_amdgcn_mfma_f32_16x16x32_f16(aw, xz, acc1[0][0], 0, 0, 0);
        float h[4], p[4];
#pragma unroll
        for (int r = 0; r < 4; ++r) {
            float bb = (ubf < HID) ? b0[ubf + r] : 0.f;
            float av = acc1[0][0][r] + bb;
            sig_sp(av, h[r], p[r]);
        }
        if (ubf < 200) *(half4v*)(&FBa[lm*FBSTR + ubf]) = pk4((float4v){h[0],h[1],h[2],h[3]});
        *(half4v*)(&Cf[0*CFSZ + lm*CSTR + ubf]) = pk4((float4v){p[0],p[1],p[2],p[3]});
    }
    __syncthreads();   // bar0

    // ========= P2: F1 || T2main (th0 on-the-fly); in-main epis =========
    if (wave < NMT) run_mv<1,1,FBSTR>(W1Tsw, FBa, wave, 1, lane, acc1);
    {
#pragma unroll
        for (int m = 0; m < 2; ++m)
#pragma unroll
            for (int n = 0; n < NT4; ++n)
                acc4[m][n] = (float4v){0.f, 0.f, 0.f, 0.f};
        for (int kc = 0; kc < NKC; ++kc) {
            half8 a[2];
#pragma unroll
            for (int m = 0; m < 2; ++m)
                if (m < mtct) a[m] = W1Tsw[(kc*NMT + mt0t + m)*64 + lane];
            half8 p0 = *(const half8*)(Cf + 0*CFSZ + lm*CSTR + kc*32 + q*8);
            half8 x[NT4];
#pragma unroll
            for (int n = 0; n < NT4; ++n) {
                half8 w0 = *(const half8*)(w0t + (twn*NT4 + n)*WSTR + kc*32 + q*8);
                x[n] = p0 * w0;
            }
#pragma unroll
            for (int m = 0; m < 2; ++m)
                if (m < mtct)
#pragma unroll
                    for (int n = 0; n < NT4; ++n)
                        acc4[m][n] = __builtin_amdgcn_mfma_f32_16x16x32_f16(a[m], x[n], acc4[m][n], 0, 0, 0);
        }
    }
#pragma unroll
    for (int m = 0; m < 2; ++m)     // T2epi: raw t1' -> Xt (Xt unread this phase)
        if (m < mtct) {
            const int ub = (mt0t + m)*16 + q*4;
#pragma unroll
            for (int n = 0; n < NT4; ++n) {
                int row = twn*64 + n*16 + lm;
                *(half4v*)(&Xt[row*XSTR + ub]) = pk4(acc4[m][n]);
            }
        }
    if (wave < NMT) {               // F1epi: h1 -> FBb, p1 -> Cf1
        half4v bb = *(const half4v*)(&bsh[1*WSTR + ubf]);
        float h[4], p[4];
#pragma unroll
        for (int r = 0; r < 4; ++r) {
            float av = acc1[0][0][r] + (float)bb[r];
            sig_sp(av, h[r], p[r]);
        }
        if (ubf < 200) *(half4v*)(&FBb[lm*FBSTR + ubf]) = pk4((float4v){h[0],h[1],h[2],h[3]});
        *(half4v*)(&Cf[1*CFSZ + lm*CSTR + ubf]) = pk4((float4v){p[0],p[1],p[2],p[3]});
    }
    __syncthreads();   // bar1

    // ========= P3: F2 || T3main (x = t1raw ⊙ p1); in-main epis =========
    if (wave < NMT) run_mv<1,1,FBSTR>(W2Tsw, FBb, wave, 1, lane, acc1);
    run_mv_mod<NT4>(W2Tsw, Xt + twn*64*XSTR, Cf + 1*CFSZ + lm*CSTR, mt0t, mtct, lane, acc4);
#pragma unroll
    for (int m = 0; m < 2; ++m)     // T3epi: raw t2'' -> Xb (Xb unread this phase)
        if (m < mtct) {
            const int ub = (mt0t + m)*16 + q*4;
#pragma unroll
            for (int n = 0; n < NT4; ++n) {
                int row = twn*64 + n*16 + lm;
                *(half4v*)(&Xb[row*XSTR + ub]) = pk4(acc4[m][n]);
            }
        }
    if (wave < NMT) {               // F2epi: d2' -> FBa, c2' -> Cf2
        half4v bb = *(const half4v*)(&bsh[2*WSTR + ubf]);
        half4v w3 = *(const half4v*)(&bsh[3*WSTR + ubf]);
        float d2[4], c2[4];
#pragma unroll
        for (int r = 0; r < 4; ++r) {
            float av = acc1[0][0][r] + (float)bb[r];
            float e = __expf(-fabsf(av));
            float rr = 1.f / (1.f + e);
            float sg = (av >= 0.f) ? rr : (1.f - rr);
            float wk = (float)w3[r];
            d2[r] = wk * sg;
            c2[r] = wk * sg * (1.f - sg);
        }
        if (ubf < 200) *(half4v*)(&FBa[lm*FBSTR + ubf]) = pk4((float4v){d2[0],d2[1],d2[2],d2[3]});
        *(half4v*)(&Cf[2*CFSZ + lm*CSTR + ubf]) = pk4((float4v){c2[0],c2[1],c2[2],c2[3]});
    }
    __syncthreads();   // bar2

    // ========= P4: B1 || T4main (x = t2raw ⊙ c2); B1epi in-main; T4epi post-bar =========
    if (wave < NMT) run_mv<1,1,FBSTR>(W2sw, FBa, wave, 1, lane, acc1);
    run_mv_mod<NT4>(W2sw, Xb + twn*64*XSTR, Cf + 2*CFSZ + lm*CSTR, mt0t, mtct, lane, acc4);
    if (wave < NMT) {               // B1epi: u1*p1 -> FBb, c3 -> Cf3
        half4v p1 = *(const half4v*)(&Cf[1*CFSZ + lm*CSTR + ubf]);
        half4v u1 = pk4(acc1[0][0]);
        if (ubf < 200) *(half4v*)(&FBb[lm*FBSTR + ubf]) = u1 * p1;
        *(half4v*)(&Cf[3*CFSZ + lm*CSTR + ubf]) = u1 * (one - p1);
    }
    __syncthreads();   // bar3
#pragma unroll
    for (int m = 0; m < 2; ++m)     // T4epi: d1dot = v1*p1 + c3*(t1raw*p1) -> Xb (final)
        if (m < mtct) {
            const int ub = (mt0t + m)*16 + q*4;
            half4v p1 = *(const half4v*)(&Cf[1*CFSZ + lm*CSTR + ub]);
            half4v c3 = *(const half4v*)(&Cf[3*CFSZ + lm*CSTR + ub]);
#pragma unroll
            for (int n = 0; n < NT4; ++n) {
                int row = twn*64 + n*16 + lm;
                half4v xt = *(const half4v*)(&Xt[row*XSTR + ub]);
                *(half4v*)(&Xb[row*XSTR + ub]) = pk4(acc4[m][n]) * p1 + c3 * (xt * p1);
            }
        }
    __syncthreads();   // bar4

    // ========= P5: B0 || T5main (plain d1dot); in-main epis =========
    if (wave < NMT) run_mv<1,1,FBSTR>(W1sw, FBb, wave, 1, lane, acc1);
    run_mv<2,NT4,XSTR>(W1sw, Xb + twn*64*XSTR, mt0t, mtct, lane, acc4);
#pragma unroll
    for (int m = 0; m < 2; ++m)     // T5epi: raw v0'' -> Xt (Xt unread this phase)
        if (m < mtct) {
            const int ub = (mt0t + m)*16 + q*4;
#pragma unroll
            for (int n = 0; n < NT4; ++n) {
                int row = twn*64 + n*16 + lm;
                *(half4v*)(&Xt[row*XSTR + ub]) = pk4(acc4[m][n]);
            }
        }
    if (wave < NMT) {               // B0epi: d0' -> FBa, c4 -> Cf4
        half4v p0 = *(const half4v*)(&Cf[0*CFSZ + lm*CSTR + ubf]);
        half4v u0 = pk4(acc1[0][0]);
        half4v d0 = u0 * p0;
        if (ubf < 200) *(half4v*)(&FBa[lm*FBSTR + ubf]) = d0;
        *(half4v*)(&Cf[4*CFSZ + lm*CSTR + ubf]) = d0 * (one - p0);
    }
    __syncthreads();   // bar5

    // ========= P6: Hr (waves 0-7, d0dot on-the-fly) || g-proj (wave 8) =========
    if (wave < 8) {
        float4v hacc = (float4v){0.f,0.f,0.f,0.f};
        for (int kc = 0; kc < NKC; ++kc) {
            half8 a  = W0sw[kc*64 + lane];
            half8 xt = *(const half8*)(Xt + (wave*16 + lm)*XSTR + kc*32 + q*8);
            half8 p0 = *(const half8*)(Cf + 0*CFSZ + lm*CSTR + kc*32 + q*8);
            half8 c4 = *(const half8*)(Cf + 4*CFSZ + lm*CSTR + kc*32 + q*8);
            half8 w0 = *(const half8*)(w0t + wave*WSTR + kc*32 + q*8);
            half8 x  = xt * p0 + c4 * w0;   // d0dot, bit-identical to R1's stored form
            hacc = __builtin_amdgcn_mfma_f32_16x16x32_f16(a, x, hacc, 0, 0, 0);
        }
        int row = wave*16 + lm;
        float4v hv;
        hv.x = hacc.x*INV_KS; hv.y = hacc.y*INV_KS;
        hv.z = hacc.z*INV_KS; hv.w = hacc.w*INV_KS;
        *(float4v*)(&Hr[row*HSTR + q*4]) = hv;   // Hr overlays dead Xb
    } else if (wave == 8) {
        float4v g = (float4v){0.f,0.f,0.f,0.f};
        for (int kc = 0; kc < NKC; ++kc) {
            half8 a = W0sw[kc*64 + lane];
            half8 x = *(const half8*)(FBa + lm*FBSTR + kc*32 + q*8);
            g = __builtin_amdgcn_mfma_f32_16x16x32_f16(a, x, g, 0, 0, 0);
        }
        if (q < 2) {
            float4v gv;
            gv.x = g.x*INV_K; gv.y = g.y*INV_K; gv.z = g.z*INV_K; gv.w = g.w*INV_K;
            *(float4v*)(&gsh[lm*8 + q*4]) = gv;
        }
    }
    __syncthreads();   // bar6

    // ========= per-sample 8x8 solve =========
    if (tid < BS) {
        const int s = tid;
        float M[DD][DD], F[DD], v[DD], a[DD];
#pragma unroll
        for (int c = 0; c < DD; ++c) v[c] = z[(s0 + s)*ZD + DD + c];
#pragma unroll
        for (int r = 0; r < DD; ++r) {
            float f = gsh[s*8 + r];
#pragma unroll
            for (int c = 0; c < DD; ++c) {
                M[r][c] = Hr[(r*16 + s)*HSTR + DD + c] + ((r == c) ? 2.f*EPSL : 0.f);
                f -= Hr[(r*16 + s)*HSTR + c] * v[c];
            }
            F[r] = f;
        }
#pragma unroll
        for (int col = 0; col < DD; ++col) {
            const float inv = 1.f / M[col][col];
#pragma unroll
            for (int r = col + 1; r < DD; ++r) {
                const float fac = M[r][col] * inv;
#pragma unroll
                for (int c = col + 1; c < DD; ++c) M[r][c] -= fac * M[col][c];
                F[r] -= fac * F[col];
            }
        }
#pragma unroll
        for (int r = DD - 1; r >= 0; --r) {
            float ssum = F[r];
#pragma unroll
            for (int c = r + 1; c < DD; ++c) ssum -= M[r][c] * a[c];
            a[r] = ssum / M[r][r];
        }
        float* op = out + (size_t)(s0 + s)*ZD;
#pragma unroll
        for (int c = 0; c < DD; ++c) { op[c] = v[c]; op[DD + c] = a[c]; }
    }
}

extern "C" void kernel_launch(void* const* d_in, const int* in_sizes, int n_in,
                              void* d_out, int out_size, void* d_ws, size_t ws_size,
                              hipStream_t stream)
{
    const float* z  = (const float*)d_in[1];
    const float* W0 = (const float*)d_in[2];
    const float* b0 = (const float*)d_in[3];
    const float* W1 = (const float*)d_in[4];
    const float* b1 = (const float*)d_in[5];
    const float* W2 = (const float*)d_in[6];
    const float* b2 = (const float*)d_in[7];
    const float* W3 = (const float*)d_in[8];
    float* out = (float*)d_out;
    _Float16* ws = (_Float16*)d_ws;

    const int n = in_sizes[1] / (2*DD);

    prep<<<dim3((WS_HALFS + 255)/256), dim3(256), 0, stream>>>(W0, W1, W2, ws);
    lnn_main<<<dim3(n / BS), dim3(NTHREADS), 0, stream>>>(
        z, W0, b0, b1, b2, W3, ws, out);
}

// Round 6
// 153.036 us; speedup vs baseline: 1.5721x; 1.0294x over previous
//
#include <hip/hip_runtime.h>
#include <math.h>

#define DD 8
#define ZD 16
#define HID 200
#define EPSL 0.1f
#define BS 16          // samples per block
#define NTHREADS 1024  // 16 waves
#define NKC 7          // K chunks of 32 (200 -> 224)
#define NMT 13         // unit tiles of 16 (200 -> 208)
#define XSTR 216       // halfs per X row (432B: 2-way-free, 16B-aligned)
#define CSTR 216       // halfs per coeff row
#define FBSTR 216      // halfs per F-chain row
#define BSTR 208       // halfs per bsh row
#define WSTR 208       // halfs per w0t row
#define HSTR 20        // floats per Hr row
#define NT4 4          // n-tiles per wave in T phase

#define KSC 1024.0f
#define SSC 64.0f
#define INV_K (1.0f/1024.0f)
#define INV_KS (1.0f/65536.0f)

typedef _Float16 half8 __attribute__((ext_vector_type(8)));
typedef _Float16 half4v __attribute__((ext_vector_type(4)));
typedef _Float16 half2v __attribute__((ext_vector_type(2)));
typedef float float4v __attribute__((ext_vector_type(4)));

#define S4 (NKC*NMT*64*8)
#define OFF_W1T 0
#define OFF_W2T (S4)
#define OFF_W1  (2*S4)
#define OFF_W2  (3*S4)
#define OFF_W0T (4*S4)
#define OFF_W0  (4*S4 + NMT*64*8)
#define WS_HALFS (4*S4 + NMT*64*8 + NKC*64*8)

// ---- LDS layout (units: _Float16). Total 81832 halfs = 163664 B ----
#define CFSZ  (16*CSTR)                  // 3456
#define FBSZ  (16*FBSTR + 8)             // 3464
#define O_XT  0                          // Xt 128 rows + 8 guard
#define O_XB  (128*XSTR + 8)             // 27656
#define O_CF  (2*(128*XSTR + 8))         // 55312: Cf[5]
#define O_U   (O_CF + 5*CFSZ)            // 72592: union{FBa,FBb | Hr 128x20 f32 | gsh}
#define O_FBA (O_U)
#define O_FBB (O_U + FBSZ)
#define O_GS  (O_U + 5120)               // gsh 16x8 f32, inside dead FBb, after Hr extent
#define O_BSH (O_U + 2*FBSZ)             // 79520: b1,b2,KSC*W3
#define O_W0T (O_BSH + 3*BSTR)           // 80144: SSC*W0[8+t][u] + 24 guard
#define SMEM_HALFS (O_W0T + 8*WSTR + 24) // 81832

// ---------------------------------------------------------------------------
__global__ void prep(const float* __restrict__ W0, const float* __restrict__ W1,
                     const float* __restrict__ W2, _Float16* __restrict__ ws)
{
    int idx = blockIdx.x * 256 + threadIdx.x;
    if (idx >= WS_HALFS) return;
    float v = 0.f;
    if (idx < 4*S4) {
        int arr = idx / S4, e = idx % S4;
        int kc = e / (NMT*64*8); int r = e % (NMT*64*8);
        int mt = r / (64*8); r %= 64*8;
        int lane = r / 8, j = r % 8;
        int m = mt*16 + (lane & 15);
        int k = kc*32 + (lane >> 4)*8 + j;
        if (m < HID && k < HID) {
            if      (arr == 0) v = W1[k*HID + m];
            else if (arr == 1) v = W2[k*HID + m];
            else if (arr == 2) v = W1[m*HID + k];
            else               v = W2[m*HID + k];
        }
    } else if (idx < OFF_W0) {
        int e = idx - OFF_W0T;
        int mt = e / (64*8); int r = e % (64*8);
        int lane = r / 8, j = r % 8;
        int m = mt*16 + (lane & 15);
        int k = (lane >> 4)*8 + j;
        if (m < HID && k < ZD) v = W0[k*HID + m];
    } else {
        int e = idx - OFF_W0;
        int kc = e / (64*8); int r = e % (64*8);
        int lane = r / 8, j = r % 8;
        int m = (lane & 15);
        int k = kc*32 + (lane >> 4)*8 + j;
        if (k < HID) v = W0[m*HID + k];
    }
    ws[idx] = (_Float16)v;
}

// ---------------------------------------------------------------------------
__device__ __forceinline__ half4v pk4(float4v a) {
    half2v lo = __builtin_bit_cast(half2v, __builtin_amdgcn_cvt_pkrtz(a.x, a.y));
    half2v hi = __builtin_bit_cast(half2v, __builtin_amdgcn_cvt_pkrtz(a.z, a.w));
    return __builtin_shufflevector(lo, hi, 0, 1, 2, 3);
}
__device__ __forceinline__ void sig_sp(float x, float& sp, float& sg) {
    float e = __expf(-fabsf(x));
    float r = 1.0f / (1.0f + e);
    sg = (x >= 0.f) ? r : (1.0f - r);
    sp = fmaxf(x, 0.f) + __logf(1.f + e);
}

// F-chain matvec (16 rows), kc=0 fragment preloaded
__device__ __forceinline__ float4v run_fv(const half8* __restrict__ Asw,
                                          const _Float16* __restrict__ FBx,
                                          int fw, int lane, half8 pa)
{
    const int lm = lane & 15, q = lane >> 4;
    float4v acc = (float4v){0.f, 0.f, 0.f, 0.f};
#pragma unroll
    for (int kc = 0; kc < NKC; ++kc) {
        half8 a = kc ? Asw[(kc*NMT + fw)*64 + lane] : pa;
        half8 x = *(const half8*)(FBx + lm*FBSTR + kc*32 + q*8);
        acc = __builtin_amdgcn_mfma_f32_16x16x32_f16(a, x, acc, 0, 0, 0);
    }
    return acc;
}

// T matvec, kc=0 fragments preloaded
template<int NT>
__device__ __forceinline__ void run_mvp(const half8* __restrict__ Asw,
                                        const _Float16* __restrict__ Xsrc,
                                        int mt0, int mtc, int lane,
                                        float4v acc[2][NT], half8 pa0, half8 pa1)
{
    const int lm = lane & 15, q = lane >> 4;
#pragma unroll
    for (int m = 0; m < 2; ++m)
#pragma unroll
        for (int n = 0; n < NT; ++n)
            acc[m][n] = (float4v){0.f, 0.f, 0.f, 0.f};
#pragma unroll
    for (int kc = 0; kc < NKC; ++kc) {
        half8 a0 = kc ? Asw[(kc*NMT + mt0)*64 + lane] : pa0;
        half8 a1 = pa1;
        if (kc && mtc > 1) a1 = Asw[(kc*NMT + mt0 + 1)*64 + lane];
        half8 x[NT];
#pragma unroll
        for (int n = 0; n < NT; ++n)
            x[n] = *(const half8*)(Xsrc + (n*16 + lm)*XSTR + kc*32 + q*8);
#pragma unroll
        for (int n = 0; n < NT; ++n)
            acc[0][n] = __builtin_amdgcn_mfma_f32_16x16x32_f16(a0, x[n], acc[0][n], 0, 0, 0);
        if (mtc > 1)
#pragma unroll
            for (int n = 0; n < NT; ++n)
                acc[1][n] = __builtin_amdgcn_mfma_f32_16x16x32_f16(a1, x[n], acc[1][n], 0, 0, 0);
    }
}

// ---------------------------------------------------------------------------
__global__ void __launch_bounds__(NTHREADS, 4)
lnn_main(const float* __restrict__ z,
         const float* __restrict__ W0, const float* __restrict__ b0,
         const float* __restrict__ b1, const float* __restrict__ b2,
         const float* __restrict__ W3,
         const _Float16* __restrict__ ws,
         float* __restrict__ out)
{
    __shared__ alignas(16) _Float16 smem[SMEM_HALFS];
    _Float16* const Xt  = smem + O_XT;
    _Float16* const Xb  = smem + O_XB;
    _Float16* const Cf  = smem + O_CF;
    _Float16* const FBa = smem + O_FBA;
    _Float16* const FBb = smem + O_FBB;
    _Float16* const bsh = smem + O_BSH;
    _Float16* const w0t = smem + O_W0T;
    float*    const gsh = (float*)(smem + O_GS);
    float*    const Hr  = (float*)(smem + O_U);   // overlays FB region (dead by P9)

    const int tid  = threadIdx.x;
    const int wave = tid >> 6;
    const int lane = tid & 63;
    const int lm   = lane & 15;
    const int q    = lane >> 4;
    const int s0   = blockIdx.x * BS;

    // T-phase wave grid: 8 m-groups x 2 n-groups
    const int twm  = wave >> 1;
    const int twn  = wave & 1;
    const int mt0t = (twm < 5) ? twm*2 : (twm + 5);
    const int mtct = (twm < 5) ? 2 : 1;

    // F-duty on waves 3..15 (SIMD balance: T units 7,7,6,6 pair with F 3,3,3,4)
    const bool fok = (wave >= 3);
    const int  fw  = fok ? (wave - 3) : 0;
    const int  ubf = fw*16 + q*4;

    const half8* W1Tsw = (const half8*)(ws + OFF_W1T);
    const half8* W2Tsw = (const half8*)(ws + OFF_W2T);
    const half8* W1sw  = (const half8*)(ws + OFF_W1);
    const half8* W2sw  = (const half8*)(ws + OFF_W2);
    const half8* W0Tsw = (const half8*)(ws + OFF_W0T);
    const half8* W0sw  = (const half8*)(ws + OFF_W0);

    const half4v one = {(_Float16)1.f,(_Float16)1.f,(_Float16)1.f,(_Float16)1.f};

    float4v acc4[2][NT4];
    float4v accF;
    half8 pT0, pT1, pF;

    // ================= P0: init staging || F0 (globals only) =================
    for (int idx = tid; idx < 128*16; idx += NTHREADS) {
        int r = idx >> 4, c = 200 + (idx & 15);
        Xt[r*XSTR + c] = (_Float16)0.f;
        Xb[r*XSTR + c] = (_Float16)0.f;
    }
    for (int idx = tid; idx < 2*16*16; idx += NTHREADS) {
        int buf = idx >> 8, r = (idx >> 4) & 15, c = 200 + (idx & 15);
        (buf ? FBb : FBa)[r*FBSTR + c] = (_Float16)0.f;
    }
    if (tid < 8) {
        Xt[128*XSTR + tid]  = (_Float16)0.f;   // row-127 kc6 overflow guards
        Xb[128*XSTR + tid]  = (_Float16)0.f;
        FBa[16*FBSTR + tid] = (_Float16)0.f;
        FBb[16*FBSTR + tid] = (_Float16)0.f;
        Cf[1*CFSZ + tid]    = (_Float16)0.f;   // Cf0 row15 spill landing pad (benign race)
    }
    for (int idx = tid; idx < 5*16*8; idx += NTHREADS) {
        int j = idx >> 7, r = (idx >> 3) & 15, c = 208 + (idx & 7);
        Cf[j*CFSZ + r*CSTR + c] = (_Float16)0.f;
    }
    for (int idx = tid; idx < 3*BSTR; idx += NTHREADS) {
        int l = idx / BSTR, u = idx % BSTR;
        float v = 0.f;
        if (u < HID) {
            if      (l == 0) v = b1[u];
            else if (l == 1) v = b2[u];
            else             v = KSC * W3[u];
        }
        bsh[idx] = (_Float16)v;
    }
    for (int idx = tid; idx < 8*WSTR + 24; idx += NTHREADS) {
        int t = idx / WSTR, u = idx % WSTR;
        w0t[idx] = (_Float16)((t < 8 && u < HID) ? SSC * W0[(DD + t)*HID + u] : 0.f);
    }
    if (fok) {   // F0: a0 = z@W0 + b0 -> FBa, p0 -> Cf0
        half8 xz;
#pragma unroll
        for (int j = 0; j < 8; ++j) xz[j] = (_Float16)0.f;
        if (q < 2) {
            const float* zp = z + (size_t)(s0 + lm)*ZD + q*8;
#pragma unroll
            for (int j = 0; j < 8; ++j) xz[j] = (_Float16)zp[j];
        }
        float4v a0v = (float4v){0.f,0.f,0.f,0.f};
        half8 aw = W0Tsw[fw*64 + lane];
        a0v = __builtin_amdgcn_mfma_f32_16x16x32_f16(aw, xz, a0v, 0, 0, 0);
        float h[4], p[4];
#pragma unroll
        for (int r = 0; r < 4; ++r) {
            float bb = (ubf < HID) ? b0[ubf + r] : 0.f;
            float av = a0v[r] + bb;
            sig_sp(av, h[r], p[r]);
        }
        *(half4v*)(&FBa[lm*FBSTR + ubf])        = pk4((float4v){h[0],h[1],h[2],h[3]});
        *(half4v*)(&Cf[0*CFSZ + lm*CSTR + ubf]) = pk4((float4v){p[0],p[1],p[2],p[3]});
    }
    pT0 = W1Tsw[mt0t*64 + lane];
    pT1 = W1Tsw[(mt0t + mtct - 1)*64 + lane];
    pF  = W1Tsw[fw*64 + lane];
    __syncthreads();   // bar0

    // ========= P2: T2main (th0 on-the-fly) || F1 (main+epi) =========
    {
#pragma unroll
        for (int m = 0; m < 2; ++m)
#pragma unroll
            for (int n = 0; n < NT4; ++n)
                acc4[m][n] = (float4v){0.f, 0.f, 0.f, 0.f};
#pragma unroll
        for (int kc = 0; kc < NKC; ++kc) {
            half8 a0 = kc ? W1Tsw[(kc*NMT + mt0t)*64 + lane] : pT0;
            half8 a1 = pT1;
            if (kc && mtct > 1) a1 = W1Tsw[(kc*NMT + mt0t + 1)*64 + lane];
            half8 p0 = *(const half8*)(Cf + 0*CFSZ + lm*CSTR + kc*32 + q*8);
            half8 x[NT4];
#pragma unroll
            for (int n = 0; n < NT4; ++n) {
                half8 w0 = *(const half8*)(w0t + (twn*NT4 + n)*WSTR + kc*32 + q*8);
                x[n] = p0 * w0;
            }
#pragma unroll
            for (int n = 0; n < NT4; ++n)
                acc4[0][n] = __builtin_amdgcn_mfma_f32_16x16x32_f16(a0, x[n], acc4[0][n], 0, 0, 0);
            if (mtct > 1)
#pragma unroll
                for (int n = 0; n < NT4; ++n)
                    acc4[1][n] = __builtin_amdgcn_mfma_f32_16x16x32_f16(a1, x[n], acc4[1][n], 0, 0, 0);
        }
    }
    if (fok) {   // F1 main + epi: h1 -> FBb, p1 -> Cf1
        accF = run_fv(W1Tsw, FBa, fw, lane, pF);
        half4v bb = *(const half4v*)(&bsh[0*BSTR + ubf]);
        float h[4], p[4];
#pragma unroll
        for (int r = 0; r < 4; ++r) {
            float av = accF[r] + (float)bb[r];
            sig_sp(av, h[r], p[r]);
        }
        *(half4v*)(&FBb[lm*FBSTR + ubf])        = pk4((float4v){h[0],h[1],h[2],h[3]});
        *(half4v*)(&Cf[1*CFSZ + lm*CSTR + ubf]) = pk4((float4v){p[0],p[1],p[2],p[3]});
    }
    pF = W2Tsw[fw*64 + lane];
    __syncthreads();   // bar1

    // ========= P3: T2epi || F2 (main+epi) =========
    if (fok) {   // F2: d2' -> FBa, c2' -> Cf2
        accF = run_fv(W2Tsw, FBb, fw, lane, pF);
        half4v bb = *(const half4v*)(&bsh[1*BSTR + ubf]);
        half4v w3 = *(const half4v*)(&bsh[2*BSTR + ubf]);
        float d2[4], c2[4];
#pragma unroll
        for (int r = 0; r < 4; ++r) {
            float av = accF[r] + (float)bb[r];
            float e = __expf(-fabsf(av));
            float rr = 1.f / (1.f + e);
            float sg = (av >= 0.f) ? rr : (1.f - rr);
            float wk = (float)w3[r];
            d2[r] = wk * sg;
            c2[r] = wk * sg * (1.f - sg);
        }
        *(half4v*)(&FBa[lm*FBSTR + ubf])        = pk4((float4v){d2[0],d2[1],d2[2],d2[3]});
        *(half4v*)(&Cf[2*CFSZ + lm*CSTR + ubf]) = pk4((float4v){c2[0],c2[1],c2[2],c2[3]});
    }
#pragma unroll
    for (int m = 0; m < 2; ++m)      // T2epi: th1 = t1'*p1 -> Xt
        if (m < mtct) {
            const int ub = (mt0t + m)*16 + q*4;
            half4v p1 = *(const half4v*)(&Cf[1*CFSZ + lm*CSTR + ub]);
#pragma unroll
            for (int n = 0; n < NT4; ++n) {
                int row = (twn*NT4 + n)*16 + lm;
                *(half4v*)(&Xt[row*XSTR + ub]) = pk4(acc4[m][n]) * p1;
            }
        }
    pT0 = W2Tsw[mt0t*64 + lane];
    pT1 = W2Tsw[(mt0t + mtct - 1)*64 + lane];
    pF  = W2sw[fw*64 + lane];
    __syncthreads();   // bar2

    // ========= P4: T3main || B1 (main+epi) =========
    run_mvp<NT4>(W2Tsw, Xt + twn*64*XSTR, mt0t, mtct, lane, acc4, pT0, pT1);
    if (fok) {   // B1: d1' = u1*p1 -> FBb, c3 -> Cf3
        accF = run_fv(W2sw, FBa, fw, lane, pF);
        half4v p1 = *(const half4v*)(&Cf[1*CFSZ + lm*CSTR + ubf]);
        half4v u1 = pk4(accF);
        *(half4v*)(&FBb[lm*FBSTR + ubf])        = u1 * p1;
        *(half4v*)(&Cf[3*CFSZ + lm*CSTR + ubf]) = u1 * (one - p1);
    }
    pF = W1sw[fw*64 + lane];
    __syncthreads();   // bar3

    // ========= P5: T3epi || B0 (main+epi) =========
    if (fok) {   // B0: d0' -> FBa, c4 -> Cf4
        accF = run_fv(W1sw, FBb, fw, lane, pF);
        half4v p0 = *(const half4v*)(&Cf[0*CFSZ + lm*CSTR + ubf]);
        half4v u0 = pk4(accF);
        half4v d0 = u0 * p0;
        *(half4v*)(&FBa[lm*FBSTR + ubf])        = d0;
        *(half4v*)(&Cf[4*CFSZ + lm*CSTR + ubf]) = d0 * (one - p0);
    }
#pragma unroll
    for (int m = 0; m < 2; ++m)      // T3epi: d2dot = t2''*c2 -> Xb
        if (m < mtct) {
            const int ub = (mt0t + m)*16 + q*4;
            half4v c2 = *(const half4v*)(&Cf[2*CFSZ + lm*CSTR + ub]);
#pragma unroll
            for (int n = 0; n < NT4; ++n) {
                int row = (twn*NT4 + n)*16 + lm;
                *(half4v*)(&Xb[row*XSTR + ub]) = pk4(acc4[m][n]) * c2;
            }
        }
    pT0 = W2sw[mt0t*64 + lane];
    pT1 = W2sw[(mt0t + mtct - 1)*64 + lane];
    if (wave == 14) pF = W0sw[lane];
    __syncthreads();   // bar4

    // ========= P6: T4main || g-projection (wave 14) =========
    run_mvp<NT4>(W2sw, Xb + twn*64*XSTR, mt0t, mtct, lane, acc4, pT0, pT1);
    if (wave == 14) {
        float4v g = (float4v){0.f,0.f,0.f,0.f};
#pragma unroll
        for (int kc = 0; kc < NKC; ++kc) {
            half8 a = kc ? W0sw[kc*64 + lane] : pF;
            half8 x = *(const half8*)(FBa + lm*FBSTR + kc*32 + q*8);
            g = __builtin_amdgcn_mfma_f32_16x16x32_f16(a, x, g, 0, 0, 0);
        }
        if (q < 2) {
            float4v gv;
            gv.x = g.x*INV_K; gv.y = g.y*INV_K; gv.z = g.z*INV_K; gv.w = g.w*INV_K;
            *(float4v*)(&gsh[lm*8 + q*4]) = gv;
        }
    }
    __syncthreads();   // bar5

    // ========= P7: T4epi =========
#pragma unroll
    for (int m = 0; m < 2; ++m)      // d1dot = v1''*p1 + c3*th1 -> Xb
        if (m < mtct) {
            const int ub = (mt0t + m)*16 + q*4;
            half4v p1 = *(const half4v*)(&Cf[1*CFSZ + lm*CSTR + ub]);
            half4v c3 = *(const half4v*)(&Cf[3*CFSZ + lm*CSTR + ub]);
#pragma unroll
            for (int n = 0; n < NT4; ++n) {
                int row = (twn*NT4 + n)*16 + lm;
                half4v th1 = *(const half4v*)(&Xt[row*XSTR + ub]);
                *(half4v*)(&Xb[row*XSTR + ub]) = pk4(acc4[m][n]) * p1 + c3 * th1;
            }
        }
    pT0 = W1sw[mt0t*64 + lane];
    pT1 = W1sw[(mt0t + mtct - 1)*64 + lane];
    __syncthreads();   // bar6

    // ========= P8: T5main + in-phase T5epi =========
    run_mvp<NT4>(W1sw, Xb + twn*64*XSTR, mt0t, mtct, lane, acc4, pT0, pT1);
#pragma unroll
    for (int m = 0; m < 2; ++m)      // d0dot = v0''*p0 + c4*w0 -> Xt (Xt unread this phase)
        if (m < mtct) {
            const int ub = (mt0t + m)*16 + q*4;
            half4v p0 = *(const half4v*)(&Cf[0*CFSZ + lm*CSTR + ub]);
            half4v c4 = *(const half4v*)(&Cf[4*CFSZ + lm*CSTR + ub]);
#pragma unroll
            for (int n = 0; n < NT4; ++n) {
                int row = (twn*NT4 + n)*16 + lm;
                half4v w0 = *(const half4v*)(&w0t[(twn*NT4 + n)*WSTR + ub]);
                *(half4v*)(&Xt[row*XSTR + ub]) = pk4(acc4[m][n]) * p0 + c4 * w0;
            }
        }
    if (wave < 8) pF = W0sw[lane];
    __syncthreads();   // bar7

    // ========= P9: Hr projection (waves 0-7; FB region dead) =========
    if (wave < 8) {
        float4v hacc = (float4v){0.f,0.f,0.f,0.f};
#pragma unroll
        for (int kc = 0; kc < NKC; ++kc) {
            half8 a = kc ? W0sw[kc*64 + lane] : pF;
            half8 x = *(const half8*)(Xt + (wave*16 + lm)*XSTR + kc*32 + q*8);
            hacc = __builtin_amdgcn_mfma_f32_16x16x32_f16(a, x, hacc, 0, 0, 0);
        }
        int row = wave*16 + lm;
        float4v hv;
        hv.x = hacc.x*INV_KS; hv.y = hacc.y*INV_KS;
        hv.z = hacc.z*INV_KS; hv.w = hacc.w*INV_KS;
        *(float4v*)(&Hr[row*HSTR + q*4]) = hv;
    }
    __syncthreads();   // bar8

    // ========= per-sample 8x8 solve =========
    if (tid < BS) {
        const int s = tid;
        float M[DD][DD], F[DD], v[DD], a[DD];
#pragma unroll
        for (int c = 0; c < DD; ++c) v[c] = z[(s0 + s)*ZD + DD + c];
#pragma unroll
        for (int r = 0; r < DD; ++r) {
            float f = gsh[s*8 + r];
#pragma unroll
            for (int c = 0; c < DD; ++c) {
                M[r][c] = Hr[(r*16 + s)*HSTR + DD + c] + ((r == c) ? 2.f*EPSL : 0.f);
                f -= Hr[(r*16 + s)*HSTR + c] * v[c];
            }
            F[r] = f;
        }
#pragma unroll
        for (int col = 0; col < DD; ++col) {
            const float inv = 1.f / M[col][col];
#pragma unroll
            for (int r = col + 1; r < DD; ++r) {
                const float fac = M[r][col] * inv;
#pragma unroll
                for (int c = col + 1; c < DD; ++c) M[r][c] -= fac * M[col][c];
                F[r] -= fac * F[col];
            }
        }
#pragma unroll
        for (int r = DD - 1; r >= 0; --r) {
            float ssum = F[r];
#pragma unroll
            for (int c = r + 1; c < DD; ++c) ssum -= M[r][c] * a[c];
            a[r] = ssum / M[r][r];
        }
        float* op = out + (size_t)(s0 + s)*ZD;
#pragma unroll
        for (int c = 0; c < DD; ++c) { op[c] = v[c]; op[DD + c] = a[c]; }
    }
}

extern "C" void kernel_launch(void* const* d_in, const int* in_sizes, int n_in,
                              void* d_out, int out_size, void* d_ws, size_t ws_size,
                              hipStream_t stream)
{
    const float* z  = (const float*)d_in[1];
    const float* W0 = (const float*)d_in[2];
    const float* b0 = (const float*)d_in[3];
    const float* W1 = (const float*)d_in[4];
    const float* b1 = (const float*)d_in[5];
    const float* W2 = (const float*)d_in[6];
    const float* b2 = (const float*)d_in[7];
    const float* W3 = (const float*)d_in[8];
    float* out = (float*)d_out;
    _Float16* ws = (_Float16*)d_ws;

    const int n = in_sizes[1] / (2*DD);

    prep<<<dim3((WS_HALFS + 255)/256), dim3(256), 0, stream>>>(W0, W1, W2, ws);
    lnn_main<<<dim3(n / BS), dim3(NTHREADS), 0, stream>>>(
        z, W0, b0, b1, b2, W3, ws, out);
}

// Round 8
// 151.298 us; speedup vs baseline: 1.5902x; 1.0115x over previous
//
#include <hip/hip_runtime.h>
#include <math.h>

#define DD 8
#define ZD 16
#define HID 200
#define EPSL 0.1f
#define BS 16          // samples per block
#define NTHREADS 1024  // 16 waves
#define NKC 7          // K chunks of 32 (200 -> 224)
#define NMT 13         // unit tiles of 16 (200 -> 208)
#define XSTR 216       // halfs per X row (432B: 2-way-free, 16B-aligned)
#define CSTR 216       // halfs per coeff row
#define FBSTR 216      // halfs per F-chain row
#define BSTR 208       // halfs per bsh row
#define WSTR 208       // halfs per w0t row
#define HSTR 20        // floats per Hr row
#define NT4 4          // n-tiles per wave in T phase

#define KSC 1024.0f
#define SSC 64.0f
#define INV_K (1.0f/1024.0f)
#define INV_KS (1.0f/65536.0f)

typedef _Float16 half8 __attribute__((ext_vector_type(8)));
typedef _Float16 half4v __attribute__((ext_vector_type(4)));
typedef _Float16 half2v __attribute__((ext_vector_type(2)));
typedef float float4v __attribute__((ext_vector_type(4)));

#define S4 (NKC*NMT*64*8)
#define OFF_W1T 0
#define OFF_W2T (S4)
#define OFF_W1  (2*S4)
#define OFF_W2  (3*S4)
#define OFF_W0T (4*S4)
#define OFF_W0  (4*S4 + NMT*64*8)
#define WS_HALFS (4*S4 + NMT*64*8 + NKC*64*8)

// ---- LDS layout (units: _Float16). Total 81832 halfs = 163664 B ----
#define CFSZ  (16*CSTR)                  // 3456
#define FBSZ  (16*FBSTR + 8)             // 3464
#define O_XT  0                          // Xt 128 rows + 8 guard
#define O_XB  (128*XSTR + 8)             // 27656
#define O_CF  (2*(128*XSTR + 8))         // 55312: Cf[5]
#define O_U   (O_CF + 5*CFSZ)            // 72592: union{FBa,FBb | Hr 128x20 f32 | gsh}
#define O_FBA (O_U)
#define O_FBB (O_U + FBSZ)
#define O_GS  (O_U + 5120)               // gsh 16x8 f32, inside dead FBb, after Hr extent
#define O_BSH (O_U + 2*FBSZ)             // 79520: b1,b2,KSC*W3
#define O_W0T (O_BSH + 3*BSTR)           // 80144: SSC*W0[8+t][u] + 24 guard
#define SMEM_HALFS (O_W0T + 8*WSTR + 24) // 81832

// ---------------------------------------------------------------------------
__global__ void prep(const float* __restrict__ W0, const float* __restrict__ W1,
                     const float* __restrict__ W2, _Float16* __restrict__ ws)
{
    int idx = blockIdx.x * 256 + threadIdx.x;
    if (idx >= WS_HALFS) return;
    float v = 0.f;
    if (idx < 4*S4) {
        int arr = idx / S4, e = idx % S4;
        int kc = e / (NMT*64*8); int r = e % (NMT*64*8);
        int mt = r / (64*8); r %= 64*8;
        int lane = r / 8, j = r % 8;
        int m = mt*16 + (lane & 15);
        int k = kc*32 + (lane >> 4)*8 + j;
        if (m < HID && k < HID) {
            if      (arr == 0) v = W1[k*HID + m];
            else if (arr == 1) v = W2[k*HID + m];
            else if (arr == 2) v = W1[m*HID + k];
            else               v = W2[m*HID + k];
        }
    } else if (idx < OFF_W0) {
        int e = idx - OFF_W0T;
        int mt = e / (64*8); int r = e % (64*8);
        int lane = r / 8, j = r % 8;
        int m = mt*16 + (lane & 15);
        int k = (lane >> 4)*8 + j;
        if (m < HID && k < ZD) v = W0[k*HID + m];
    } else {
        int e = idx - OFF_W0;
        int kc = e / (64*8); int r = e % (64*8);
        int lane = r / 8, j = r % 8;
        int m = (lane & 15);
        int k = kc*32 + (lane >> 4)*8 + j;
        if (k < HID) v = W0[m*HID + k];
    }
    ws[idx] = (_Float16)v;
}

// ---------------------------------------------------------------------------
__device__ __forceinline__ half4v pk4(float4v a) {
    half2v lo = __builtin_bit_cast(half2v, __builtin_amdgcn_cvt_pkrtz(a.x, a.y));
    half2v hi = __builtin_bit_cast(half2v, __builtin_amdgcn_cvt_pkrtz(a.z, a.w));
    return __builtin_shufflevector(lo, hi, 0, 1, 2, 3);
}
__device__ __forceinline__ void sig_sp(float x, float& sp, float& sg) {
    float e = __expf(-fabsf(x));
    float r = 1.0f / (1.0f + e);
    sg = (x >= 0.f) ? r : (1.0f - r);
    sp = fmaxf(x, 0.f) + __logf(1.f + e);
}

// F-chain matvec (16 rows), kc=0 fragment preloaded; setprio(1) inside
__device__ __forceinline__ float4v run_fv(const half8* __restrict__ Asw,
                                          const _Float16* __restrict__ FBx,
                                          int fw, int lane, half8 pa)
{
    const int lm = lane & 15, q = lane >> 4;
    float4v acc = (float4v){0.f, 0.f, 0.f, 0.f};
    __builtin_amdgcn_s_setprio(1);
#pragma unroll
    for (int kc = 0; kc < NKC; ++kc) {
        half8 a = kc ? Asw[(kc*NMT + fw)*64 + lane] : pa;
        half8 x = *(const half8*)(FBx + lm*FBSTR + kc*32 + q*8);
        acc = __builtin_amdgcn_mfma_f32_16x16x32_f16(a, x, acc, 0, 0, 0);
    }
    __builtin_amdgcn_s_setprio(0);
    return acc;
}

// T matvec, kc=0 fragments preloaded
template<int NT>
__device__ __forceinline__ void run_mvp(const half8* __restrict__ Asw,
                                        const _Float16* __restrict__ Xsrc,
                                        int mt0, int mtc, int lane,
                                        float4v acc[2][NT], half8 pa0, half8 pa1)
{
    const int lm = lane & 15, q = lane >> 4;
#pragma unroll
    for (int m = 0; m < 2; ++m)
#pragma unroll
        for (int n = 0; n < NT; ++n)
            acc[m][n] = (float4v){0.f, 0.f, 0.f, 0.f};
#pragma unroll
    for (int kc = 0; kc < NKC; ++kc) {
        half8 a0 = kc ? Asw[(kc*NMT + mt0)*64 + lane] : pa0;
        half8 a1 = pa1;
        if (kc && mtc > 1) a1 = Asw[(kc*NMT + mt0 + 1)*64 + lane];
        half8 x[NT];
#pragma unroll
        for (int n = 0; n < NT; ++n)
            x[n] = *(const half8*)(Xsrc + (n*16 + lm)*XSTR + kc*32 + q*8);
#pragma unroll
        for (int n = 0; n < NT; ++n)
            acc[0][n] = __builtin_amdgcn_mfma_f32_16x16x32_f16(a0, x[n], acc[0][n], 0, 0, 0);
        if (mtc > 1)
#pragma unroll
            for (int n = 0; n < NT; ++n)
                acc[1][n] = __builtin_amdgcn_mfma_f32_16x16x32_f16(a1, x[n], acc[1][n], 0, 0, 0);
    }
}

// ---------------------------------------------------------------------------
__global__ void __launch_bounds__(NTHREADS, 4)
lnn_main(const float* __restrict__ z,
         const float* __restrict__ W0, const float* __restrict__ b0,
         const float* __restrict__ b1, const float* __restrict__ b2,
         const float* __restrict__ W3,
         const _Float16* __restrict__ ws,
         float* __restrict__ out)
{
    __shared__ alignas(16) _Float16 smem[SMEM_HALFS];
    _Float16* const Xt  = smem + O_XT;
    _Float16* const Xb  = smem + O_XB;
    _Float16* const Cf  = smem + O_CF;
    _Float16* const FBa = smem + O_FBA;
    _Float16* const FBb = smem + O_FBB;
    _Float16* const bsh = smem + O_BSH;
    _Float16* const w0t = smem + O_W0T;
    float*    const gsh = (float*)(smem + O_GS);
    float*    const Hr  = (float*)(smem + O_U);   // overlays FB region (dead by P9)

    const int tid  = threadIdx.x;
    const int wave = tid >> 6;
    const int lane = tid & 63;
    const int lm   = lane & 15;
    const int q    = lane >> 4;
    const int s0   = blockIdx.x * BS;

    // T-phase wave grid: 8 m-groups x 2 n-groups
    const int twm  = wave >> 1;
    const int twn  = wave & 1;
    const int mt0t = (twm < 5) ? twm*2 : (twm + 5);
    const int mtct = (twm < 5) ? 2 : 1;

    // F-duty on waves 3..15 (SIMD balance)
    const bool fok = (wave >= 3);
    const int  fw  = fok ? (wave - 3) : 0;
    const int  ubf = fw*16 + q*4;

    const half8* W1Tsw = (const half8*)(ws + OFF_W1T);
    const half8* W2Tsw = (const half8*)(ws + OFF_W2T);
    const half8* W1sw  = (const half8*)(ws + OFF_W1);
    const half8* W2sw  = (const half8*)(ws + OFF_W2);
    const half8* W0Tsw = (const half8*)(ws + OFF_W0T);
    const half8* W0sw  = (const half8*)(ws + OFF_W0);

    const half4v one = {(_Float16)1.f,(_Float16)1.f,(_Float16)1.f,(_Float16)1.f};

    float4v acc4[2][NT4];
    float4v accF;
    half8 pT0, pT1, pF;

    // ================= P0: init staging || F0 (globals only) =================
    for (int idx = tid; idx < 128*16; idx += NTHREADS) {
        int r = idx >> 4, c = 200 + (idx & 15);
        Xt[r*XSTR + c] = (_Float16)0.f;
        Xb[r*XSTR + c] = (_Float16)0.f;
    }
    for (int idx = tid; idx < 2*16*16; idx += NTHREADS) {
        int buf = idx >> 8, r = (idx >> 4) & 15, c = 200 + (idx & 15);
        (buf ? FBb : FBa)[r*FBSTR + c] = (_Float16)0.f;
    }
    if (tid < 8) {
        Xt[128*XSTR + tid]  = (_Float16)0.f;   // row-127 kc6 overflow guards
        Xb[128*XSTR + tid]  = (_Float16)0.f;
        FBa[16*FBSTR + tid] = (_Float16)0.f;
        FBb[16*FBSTR + tid] = (_Float16)0.f;
        Cf[1*CFSZ + tid]    = (_Float16)0.f;   // Cf0 row15 spill landing pad (benign race)
    }
    for (int idx = tid; idx < 5*16*8; idx += NTHREADS) {
        int j = idx >> 7, r = (idx >> 3) & 15, c = 208 + (idx & 7);
        Cf[j*CFSZ + r*CSTR + c] = (_Float16)0.f;
    }
    for (int idx = tid; idx < 3*BSTR; idx += NTHREADS) {
        int l = idx / BSTR, u = idx % BSTR;
        float v = 0.f;
        if (u < HID) {
            if      (l == 0) v = b1[u];
            else if (l == 1) v = b2[u];
            else             v = KSC * W3[u];
        }
        bsh[idx] = (_Float16)v;
    }
    for (int idx = tid; idx < 8*WSTR + 24; idx += NTHREADS) {
        int t = idx / WSTR, u = idx % WSTR;
        w0t[idx] = (_Float16)((t < 8 && u < HID) ? SSC * W0[(DD + t)*HID + u] : 0.f);
    }
    if (fok) {   // F0: a0 = z@W0 + b0 -> FBa, p0 -> Cf0
        half8 xz;
#pragma unroll
        for (int j = 0; j < 8; ++j) xz[j] = (_Float16)0.f;
        if (q < 2) {
            const float* zp = z + (size_t)(s0 + lm)*ZD + q*8;
#pragma unroll
            for (int j = 0; j < 8; ++j) xz[j] = (_Float16)zp[j];
        }
        float4v a0v = (float4v){0.f,0.f,0.f,0.f};
        half8 aw = W0Tsw[fw*64 + lane];
        a0v = __builtin_amdgcn_mfma_f32_16x16x32_f16(aw, xz, a0v, 0, 0, 0);
        float h[4], p[4];
#pragma unroll
        for (int r = 0; r < 4; ++r) {
            float bb = (ubf < HID) ? b0[ubf + r] : 0.f;
            float av = a0v[r] + bb;
            sig_sp(av, h[r], p[r]);
        }
        *(half4v*)(&FBa[lm*FBSTR + ubf])        = pk4((float4v){h[0],h[1],h[2],h[3]});
        *(half4v*)(&Cf[0*CFSZ + lm*CSTR + ubf]) = pk4((float4v){p[0],p[1],p[2],p[3]});
    }
    pT0 = W1Tsw[mt0t*64 + lane];
    pT1 = W1Tsw[(mt0t + mtct - 1)*64 + lane];
    pF  = W1Tsw[fw*64 + lane];
    __syncthreads();   // bar0

    // ========= P2: T2main (th0 on-the-fly) || F1 (main+epi) =========
    {
#pragma unroll
        for (int m = 0; m < 2; ++m)
#pragma unroll
            for (int n = 0; n < NT4; ++n)
                acc4[m][n] = (float4v){0.f, 0.f, 0.f, 0.f};
#pragma unroll
        for (int kc = 0; kc < NKC; ++kc) {
            half8 a0 = kc ? W1Tsw[(kc*NMT + mt0t)*64 + lane] : pT0;
            half8 a1 = pT1;
            if (kc && mtct > 1) a1 = W1Tsw[(kc*NMT + mt0t + 1)*64 + lane];
            half8 p0 = *(const half8*)(Cf + 0*CFSZ + lm*CSTR + kc*32 + q*8);
            half8 x[NT4];
#pragma unroll
            for (int n = 0; n < NT4; ++n) {
                half8 w0 = *(const half8*)(w0t + (twn*NT4 + n)*WSTR + kc*32 + q*8);
                x[n] = p0 * w0;
            }
#pragma unroll
            for (int n = 0; n < NT4; ++n)
                acc4[0][n] = __builtin_amdgcn_mfma_f32_16x16x32_f16(a0, x[n], acc4[0][n], 0, 0, 0);
            if (mtct > 1)
#pragma unroll
                for (int n = 0; n < NT4; ++n)
                    acc4[1][n] = __builtin_amdgcn_mfma_f32_16x16x32_f16(a1, x[n], acc4[1][n], 0, 0, 0);
        }
    }
    if (fok) {   // F1 main + epi: h1 -> FBb, p1 -> Cf1
        accF = run_fv(W1Tsw, FBa, fw, lane, pF);
        half4v bb = *(const half4v*)(&bsh[0*BSTR + ubf]);
        float h[4], p[4];
#pragma unroll
        for (int r = 0; r < 4; ++r) {
            float av = accF[r] + (float)bb[r];
            sig_sp(av, h[r], p[r]);
        }
        *(half4v*)(&FBb[lm*FBSTR + ubf])        = pk4((float4v){h[0],h[1],h[2],h[3]});
        *(half4v*)(&Cf[1*CFSZ + lm*CSTR + ubf]) = pk4((float4v){p[0],p[1],p[2],p[3]});
    }
    pF = W2Tsw[fw*64 + lane];
    __syncthreads();   // bar1

    // ========= P3: T2epi || F2 (main+epi) =========
    if (fok) {   // F2: d2' -> FBa, c2' -> Cf2
        accF = run_fv(W2Tsw, FBb, fw, lane, pF);
        half4v bb = *(const half4v*)(&bsh[1*BSTR + ubf]);
        half4v w3 = *(const half4v*)(&bsh[2*BSTR + ubf]);
        float d2[4], c2[4];
#pragma unroll
        for (int r = 0; r < 4; ++r) {
            float av = accF[r] + (float)bb[r];
            float e = __expf(-fabsf(av));
            float rr = 1.f / (1.f + e);
            float sg = (av >= 0.f) ? rr : (1.f - rr);
            float wk = (float)w3[r];
            d2[r] = wk * sg;
            c2[r] = wk * sg * (1.f - sg);
        }
        *(half4v*)(&FBa[lm*FBSTR + ubf])        = pk4((float4v){d2[0],d2[1],d2[2],d2[3]});
        *(half4v*)(&Cf[2*CFSZ + lm*CSTR + ubf]) = pk4((float4v){c2[0],c2[1],c2[2],c2[3]});
    }
#pragma unroll
    for (int m = 0; m < 2; ++m)      // T2epi: th1 = t1'*p1 -> Xt
        if (m < mtct) {
            const int ub = (mt0t + m)*16 + q*4;
            half4v p1 = *(const half4v*)(&Cf[1*CFSZ + lm*CSTR + ub]);
#pragma unroll
            for (int n = 0; n < NT4; ++n) {
                int row = (twn*NT4 + n)*16 + lm;
                *(half4v*)(&Xt[row*XSTR + ub]) = pk4(acc4[m][n]) * p1;
            }
        }
    pT0 = W2Tsw[mt0t*64 + lane];
    pT1 = W2Tsw[(mt0t + mtct - 1)*64 + lane];
    pF  = W2sw[fw*64 + lane];
    __syncthreads();   // bar2

    // ========= P4: T3main || B1 (main+epi) =========
    run_mvp<NT4>(W2Tsw, Xt + twn*64*XSTR, mt0t, mtct, lane, acc4, pT0, pT1);
    if (fok) {   // B1: d1' = u1*p1 -> FBb, c3 -> Cf3
        accF = run_fv(W2sw, FBa, fw, lane, pF);
        half4v p1 = *(const half4v*)(&Cf[1*CFSZ + lm*CSTR + ubf]);
        half4v u1 = pk4(accF);
        *(half4v*)(&FBb[lm*FBSTR + ubf])        = u1 * p1;
        *(half4v*)(&Cf[3*CFSZ + lm*CSTR + ubf]) = u1 * (one - p1);
    }
    pF = W1sw[fw*64 + lane];
    __syncthreads();   // bar3

    // ========= P5: T3epi || B0 (main+epi) =========
    if (fok) {   // B0: d0' -> FBa, c4 -> Cf4
        accF = run_fv(W1sw, FBb, fw, lane, pF);
        half4v p0 = *(const half4v*)(&Cf[0*CFSZ + lm*CSTR + ubf]);
        half4v u0 = pk4(accF);
        half4v d0 = u0 * p0;
        *(half4v*)(&FBa[lm*FBSTR + ubf])        = d0;
        *(half4v*)(&Cf[4*CFSZ + lm*CSTR + ubf]) = d0 * (one - p0);
    }
#pragma unroll
    for (int m = 0; m < 2; ++m)      // T3epi: d2dot = t2''*c2 -> Xb
        if (m < mtct) {
            const int ub = (mt0t + m)*16 + q*4;
            half4v c2 = *(const half4v*)(&Cf[2*CFSZ + lm*CSTR + ub]);
#pragma unroll
            for (int n = 0; n < NT4; ++n) {
                int row = (twn*NT4 + n)*16 + lm;
                *(half4v*)(&Xb[row*XSTR + ub]) = pk4(acc4[m][n]) * c2;
            }
        }
    pT0 = W2sw[mt0t*64 + lane];
    pT1 = W2sw[(mt0t + mtct - 1)*64 + lane];
    if (wave == 14) pF = W0sw[lane];
    __syncthreads();   // bar4

    // ========= P6: T4main || g-proj (wave 14); T4epi IN-PLACE in Xt =========
    // T4epi reads th1 from Xt[own rows x own cols] and overwrites the SAME
    // elements with d1dot: exact per-wave partition (rows by twn, cols by twm),
    // and nothing else reads Xt this phase -> no barrier needed before it.
    run_mvp<NT4>(W2sw, Xb + twn*64*XSTR, mt0t, mtct, lane, acc4, pT0, pT1);
    if (wave == 14) {
        float4v g = (float4v){0.f,0.f,0.f,0.f};
        __builtin_amdgcn_s_setprio(1);
#pragma unroll
        for (int kc = 0; kc < NKC; ++kc) {
            half8 a = kc ? W0sw[kc*64 + lane] : pF;
            half8 x = *(const half8*)(FBa + lm*FBSTR + kc*32 + q*8);
            g = __builtin_amdgcn_mfma_f32_16x16x32_f16(a, x, g, 0, 0, 0);
        }
        __builtin_amdgcn_s_setprio(0);
        if (q < 2) {
            float4v gv;
            gv.x = g.x*INV_K; gv.y = g.y*INV_K; gv.z = g.z*INV_K; gv.w = g.w*INV_K;
            *(float4v*)(&gsh[lm*8 + q*4]) = gv;
        }
    }
#pragma unroll
    for (int m = 0; m < 2; ++m)      // T4epi: d1dot = v1''*p1 + c3*th1 -> Xt (in-place)
        if (m < mtct) {
            const int ub = (mt0t + m)*16 + q*4;
            half4v p1 = *(const half4v*)(&Cf[1*CFSZ + lm*CSTR + ub]);
            half4v c3 = *(const half4v*)(&Cf[3*CFSZ + lm*CSTR + ub]);
#pragma unroll
            for (int n = 0; n < NT4; ++n) {
                int row = (twn*NT4 + n)*16 + lm;
                half4v th1 = *(const half4v*)(&Xt[row*XSTR + ub]);
                *(half4v*)(&Xt[row*XSTR + ub]) = pk4(acc4[m][n]) * p1 + c3 * th1;
            }
        }
    pT0 = W1sw[mt0t*64 + lane];
    pT1 = W1sw[(mt0t + mtct - 1)*64 + lane];
    __syncthreads();   // bar5

    // ========= P8: T5main (reads Xt=d1dot) + in-phase T5epi (writes Xb=d0dot) =========
    run_mvp<NT4>(W1sw, Xt + twn*64*XSTR, mt0t, mtct, lane, acc4, pT0, pT1);
#pragma unroll
    for (int m = 0; m < 2; ++m)      // d0dot = v0''*p0 + c4*w0 -> Xb (Xb unread this phase)
        if (m < mtct) {
            const int ub = (mt0t + m)*16 + q*4;
            half4v p0 = *(const half4v*)(&Cf[0*CFSZ + lm*CSTR + ub]);
            half4v c4 = *(const half4v*)(&Cf[4*CFSZ + lm*CSTR + ub]);
#pragma unroll
            for (int n = 0; n < NT4; ++n) {
                int row = (twn*NT4 + n)*16 + lm;
                half4v w0 = *(const half4v*)(&w0t[(twn*NT4 + n)*WSTR + ub]);
                *(half4v*)(&Xb[row*XSTR + ub]) = pk4(acc4[m][n]) * p0 + c4 * w0;
            }
        }
    if (wave < 8) pF = W0sw[lane];
    __syncthreads();   // bar6

    // ========= P9: Hr projection (waves 0-7; reads Xb; FB region dead) =========
    if (wave < 8) {
        float4v hacc = (float4v){0.f,0.f,0.f,0.f};
#pragma unroll
        for (int kc = 0; kc < NKC; ++kc) {
            half8 a = kc ? W0sw[kc*64 + lane] : pF;
            half8 x = *(const half8*)(Xb + (wave*16 + lm)*XSTR + kc*32 + q*8);
            hacc = __builtin_amdgcn_mfma_f32_16x16x32_f16(a, x, hacc, 0, 0, 0);
        }
        int row = wave*16 + lm;
        float4v hv;
        hv.x = hacc.x*INV_KS; hv.y = hacc.y*INV_KS;
        hv.z = hacc.z*INV_KS; hv.w = hacc.w*INV_KS;
        *(float4v*)(&Hr[row*HSTR + q*4]) = hv;
    }
    __syncthreads();   // bar7

    // ========= per-sample 8x8 solve =========
    if (tid < BS) {
        const int s = tid;
        float M[DD][DD], F[DD], v[DD], a[DD];
#pragma unroll
        for (int c = 0; c < DD; ++c) v[c] = z[(s0 + s)*ZD + DD + c];
#pragma unroll
        for (int r = 0; r < DD; ++r) {
            float f = gsh[s*8 + r];
#pragma unroll
            for (int c = 0; c < DD; ++c) {
                M[r][c] = Hr[(r*16 + s)*HSTR + DD + c] + ((r == c) ? 2.f*EPSL : 0.f);
                f -= Hr[(r*16 + s)*HSTR + c] * v[c];
            }
            F[r] = f;
        }
#pragma unroll
        for (int col = 0; col < DD; ++col) {
            const float inv = 1.f / M[col][col];
#pragma unroll
            for (int r = col + 1; r < DD; ++r) {
                const float fac = M[r][col] * inv;
#pragma unroll
                for (int c = col + 1; c < DD; ++c) M[r][c] -= fac * M[col][c];
                F[r] -= fac * F[col];
            }
        }
#pragma unroll
        for (int r = DD - 1; r >= 0; --r) {
            float ssum = F[r];
#pragma unroll
            for (int c = r + 1; c < DD; ++c) ssum -= M[r][c] * a[c];
            a[r] = ssum / M[r][r];
        }
        float* op = out + (size_t)(s0 + s)*ZD;
#pragma unroll
        for (int c = 0; c < DD; ++c) { op[c] = v[c]; op[DD + c] = a[c]; }
    }
}

extern "C" void kernel_launch(void* const* d_in, const int* in_sizes, int n_in,
                              void* d_out, int out_size, void* d_ws, size_t ws_size,
                              hipStream_t stream)
{
    const float* z  = (const float*)d_in[1];
    const float* W0 = (const float*)d_in[2];
    const float* b0 = (const float*)d_in[3];
    const float* W1 = (const float*)d_in[4];
    const float* b1 = (const float*)d_in[5];
    const float* W2 = (const float*)d_in[6];
    const float* b2 = (const float*)d_in[7];
    const float* W3 = (const float*)d_in[8];
    float* out = (float*)d_out;
    _Float16* ws = (_Float16*)d_ws;

    const int n = in_sizes[1] / (2*DD);

    prep<<<dim3((WS_HALFS + 255)/256), dim3(256), 0, stream>>>(W0, W1, W2, ws);
    lnn_main<<<dim3(n / BS), dim3(NTHREADS), 0, stream>>>(
        z, W0, b0, b1, b2, W3, ws, out);
}